// Round 23
// baseline (173.273 us; speedup 1.0000x reference)
//
#include <hip/hip_runtime.h>
#include <math.h>

#define WF 64

// hardware-native silu: v_exp_f32 (2^x) + v_rcp_f32 — ~5 VALU ops, ~1ulp
__device__ __forceinline__ float silu_f(float v){
  float e = __builtin_amdgcn_exp2f(v * -1.44269504088896340736f);
  return v * __builtin_amdgcn_rcpf(1.0f + e);
}

typedef __attribute__((ext_vector_type(8))) short bf16x8;
typedef __attribute__((ext_vector_type(4))) float f32x4;

__device__ __forceinline__ void bf16split(float v, unsigned short& h, unsigned short& l){
  unsigned int b = __float_as_uint(v);
  unsigned int hh = (b + 0x8000u) >> 16;
  float hf = __uint_as_float(hh << 16);
  float lo = v - hf;
  unsigned int bl = __float_as_uint(lo);
  h = (unsigned short)hh;
  l = (unsigned short)((bl + 0x8000u) >> 16);
}

// ---------- CSR count + W2 conversion (merged grids; independent work) ----------
__global__ __launch_bounds__(256) void k_count_wconv(const int* __restrict__ dst, int* __restrict__ cnt, int E,
                       const float* __restrict__ W2,
                       unsigned short* __restrict__ w2th, unsigned short* __restrict__ w2tl,
                       int nCountBlocks){
  int b = blockIdx.x;
  if (b < nCountBlocks){
    int e = b*256 + threadIdx.x;
    if (e < E) atomicAdd(&cnt[dst[e]], 1);
  } else {
    int idx = (b - nCountBlocks)*256 + threadIdx.x;
    if (idx < 224*128){
      int f = idx >> 7, k = idx & 127;
      float v = (f < 200 && k < 100) ? W2[(size_t)k*200 + f] : 0.f;
      unsigned short h, l;
      bf16split(v, h, l);
      w2th[idx] = h;
      w2tl[idx] = l;
    }
  }
}

// block-local exclusive scan over chunks of 2048 (256 thr x 8 items)
__global__ __launch_bounds__(256) void k_scan1(const int* __restrict__ cnt, int* __restrict__ rowstart, int* __restrict__ bsum, int N){
  __shared__ int s[256];
  int tid = threadIdx.x;
  int base = blockIdx.x*2048 + tid*8;
  int loc[8]; int tsum = 0;
#pragma unroll
  for (int j=0;j<8;++j){ int idx=base+j; int v = (idx<N)?cnt[idx]:0; loc[j]=tsum; tsum+=v; }
  s[tid]=tsum; __syncthreads();
  for (int off=1; off<256; off<<=1){
    int v = (tid>=off)? s[tid-off] : 0;
    __syncthreads();
    s[tid] += v;
    __syncthreads();
  }
  int texc = s[tid] - tsum;
  if (tid==255) bsum[blockIdx.x] = s[255];
#pragma unroll
  for (int j=0;j<8;++j){ int idx=base+j; if (idx<N) rowstart[idx] = texc + loc[j]; }
}

// scan3: adds block prefix (from bsum), writes cursor and dxp = {di, di*x}
__global__ __launch_bounds__(256) void k_scan3(const int* __restrict__ bsum, const int* __restrict__ cnt,
                        const float* __restrict__ x,
                        int* __restrict__ rowstart, int* __restrict__ cursor,
                        float4* __restrict__ dxp,
                        int N, int E, int nb){
  __shared__ int boffs;
  int tid = threadIdx.x;
  int b = (blockIdx.x*blockDim.x) >> 11;   // uniform within block (256 <= 2048)
  if (tid < WF){
    int v = (tid < nb && tid < b) ? bsum[tid] : 0;
#pragma unroll
    for (int off=32; off; off>>=1) v += __shfl_down(v, off);
    if (tid==0) boffs = v;
  }
  __syncthreads();
  int idx = blockIdx.x*blockDim.x + tid;
  if (idx < N){
    int v = rowstart[idx] + boffs;
    rowstart[idx]=v; cursor[idx]=v;
    float di = rsqrtf((float)(cnt[idx]+1));   // +1 self-loop
    float4 o;
    o.x = di;
    o.y = di*x[3*idx+0];
    o.z = di*x[3*idx+1];
    o.w = di*x[3*idx+2];
    dxp[idx] = o;
  }
  if (idx==0) rowstart[N]=E;
}

// fill CSR: minimum scatter — one 4B colsrc write + cursor atomic per edge
__global__ __launch_bounds__(256) void k_fill(const int* __restrict__ src, const int* __restrict__ dst,
                       int* __restrict__ cursor, int* __restrict__ colsrc, int E){
  int e = blockIdx.x*blockDim.x + threadIdx.x;
  if (e < E){
    int d = dst[e];
    int pos = atomicAdd(&cursor[d], 1);
    colsrc[pos] = src[e];
  }
}

// ---------- z1: layer-1 aggregated input (3-dim CSR walk over dxp) ----------
__global__ __launch_bounds__(256) void k_z1(const float4* __restrict__ dxp,
                     const int* __restrict__ rowstart, const int* __restrict__ colsrc,
                     float4* __restrict__ z1, int N){
  int i = blockIdx.x*blockDim.x + threadIdx.x;
  if (i >= N) return;
  float4 self = dxp[i];
  float di = self.x;
  float sx = self.y, sy = self.z, sz = self.w;
  int jb = rowstart[i], je = rowstart[i+1];
  int j = jb;
  for (; j+3 < je; j += 4){
    float4 r0 = dxp[colsrc[j]];
    float4 r1 = dxp[colsrc[j+1]];
    float4 r2 = dxp[colsrc[j+2]];
    float4 r3 = dxp[colsrc[j+3]];
    sx += (r0.y + r1.y) + (r2.y + r3.y);
    sy += (r0.z + r1.z) + (r2.z + r3.z);
    sz += (r0.w + r1.w) + (r2.w + r3.w);
  }
  for (; j < je; ++j){
    float4 r = dxp[colsrc[j]];
    sx += r.y; sy += r.z; sz += r.w;
  }
  float4 o;
  o.x = di;
  o.y = di*sx; o.z = di*sy; o.w = di*sz;
  z1[i] = o;
}

// ---------- FUSED layer-1 transform + layer-2 aggregation -> bf16 planes ----------
// HALF-WAVE per node; 4x-unrolled neighbor loop for load ILP.
__global__ __launch_bounds__(256) void k_agg2f(const float4* __restrict__ z1,
                       const int* __restrict__ rowstart, const int* __restrict__ colsrc,
                       const float* __restrict__ W1, const float* __restrict__ b1,
                       unsigned short* __restrict__ a2h, unsigned short* __restrict__ a2l, int N){
  __shared__ float w[300];
  __shared__ float bb[100];
  int tid = threadIdx.x;
  for (int t=tid; t<300; t+=256) w[t]=W1[t];
  for (int t=tid; t<100; t+=256) bb[t]=b1[t];
  __syncthreads();

  int node = blockIdx.x*8 + (tid >> 5);
  int lane = tid & 31;
  if (node >= N) return;
  if (lane >= 25){
    int ko = 100 + (lane-25)*4;
    ushort4 z = make_ushort4(0,0,0,0);
    *(ushort4*)(a2h + (size_t)node*128 + ko) = z;
    *(ushort4*)(a2l + (size_t)node*128 + ko) = z;
    return;
  }
  int f0 = lane*4;
  float w0[4], w1[4], w2[4], b[4];
#pragma unroll
  for (int j=0;j<4;++j){
    w0[j] = w[f0+j]; w1[j] = w[100+f0+j]; w2[j] = w[200+f0+j]; b[j] = bb[f0+j];
  }

  float4 zn = z1[node];
  float din = zn.x;
  float acc[4];
#pragma unroll
  for (int j=0;j<4;++j){
    float h = silu_f(zn.y*w0[j] + zn.z*w1[j] + zn.w*w2[j] + b[j]);
    acc[j] = din*h;
  }
  int jb = rowstart[node], je = rowstart[node+1];
  int e = jb;
  for (; e+3 < je; e += 4){
    float4 zu0 = z1[colsrc[e]];
    float4 zu1 = z1[colsrc[e+1]];
    float4 zu2 = z1[colsrc[e+2]];
    float4 zu3 = z1[colsrc[e+3]];
#pragma unroll
    for (int j=0;j<4;++j){
      float h0 = silu_f(zu0.y*w0[j] + zu0.z*w1[j] + zu0.w*w2[j] + b[j]);
      float h1v = silu_f(zu1.y*w0[j] + zu1.z*w1[j] + zu1.w*w2[j] + b[j]);
      float h2v = silu_f(zu2.y*w0[j] + zu2.z*w1[j] + zu2.w*w2[j] + b[j]);
      float h3v = silu_f(zu3.y*w0[j] + zu3.z*w1[j] + zu3.w*w2[j] + b[j]);
      acc[j] += (zu0.x*h0 + zu1.x*h1v) + (zu2.x*h2v + zu3.x*h3v);
    }
  }
  for (; e < je; ++e){
    float4 zu = z1[colsrc[e]];
#pragma unroll
    for (int j=0;j<4;++j){
      float h = silu_f(zu.y*w0[j] + zu.z*w1[j] + zu.w*w2[j] + b[j]);
      acc[j] += zu.x*h;
    }
  }
  ushort4 h4, l4;
  bf16split(din*acc[0], h4.x, l4.x);
  bf16split(din*acc[1], h4.y, l4.y);
  bf16split(din*acc[2], h4.z, l4.z);
  bf16split(din*acc[3], h4.w, l4.w);
  *(ushort4*)(a2h + (size_t)node*128 + f0) = h4;
  *(ushort4*)(a2l + (size_t)node*128 + f0) = l4;
}

// ---------- layer 2 matmul via split-bf16 MFMA + fused mean-pool ----------
// ONE fb PER BLOCK (R15's parallelism) + per-XCD A-grouping (R16's traffic):
// grid = nwg*7; hardware assigns block orig -> XCD orig&7; we linearize L
// within each XCD's chunk so the 7 blocks sharing an A-tile (g = L/7) are
// consecutive ON THE SAME XCD -> A re-reads hit that XCD's L2, HBM fetches
// A once (~26 MB). Single 2-barrier epilogue per block.
__global__ __launch_bounds__(128) void k_mm2(const unsigned short* __restrict__ a2h,
                      const unsigned short* __restrict__ a2l,
                      const unsigned short* __restrict__ w2th,
                      const unsigned short* __restrict__ w2tl,
                      const float* __restrict__ b2, const int* __restrict__ batch,
                      float* __restrict__ pooled, int N, int total){
  __shared__ float plL[256];
  int tid = threadIdx.x;
  int l = tid & 63, w = tid >> 6;   // w in {0,1}
  // per-XCD linearization: orig -> (xcd, idx) -> chunk-local L -> (g, fb)
  int orig = blockIdx.x;
  int q = total >> 3, r = total & 7;
  int xcd = orig & 7, idx = orig >> 3;
  int L = ((xcd < r) ? xcd*(q+1) : r*(q+1) + (xcd-r)*q) + idx;
  int g  = L / 7;
  int fb = L - g*7;
  int n0 = g * 32;
  int row = l & 15;
  int kg  = l >> 4;

  // zero plL (published by the post-MFMA barrier)
  for (int i2 = tid; i2 < 256; i2 += 128) plL[i2] = 0.f;

  const unsigned short* ah_p = a2h + (size_t)(n0 + w*16 + row)*128;
  const unsigned short* al_p = a2l + (size_t)(n0 + w*16 + row)*128;
  int gf0 = fb*32 + row, gf1 = gf0 + 16;
  const unsigned short* wh0_p = w2th + (size_t)gf0*128;
  const unsigned short* wl0_p = w2tl + (size_t)gf0*128;
  const unsigned short* wh1_p = w2th + (size_t)gf1*128;
  const unsigned short* wl1_p = w2tl + (size_t)gf1*128;

  f32x4 acc0 = {0.f,0.f,0.f,0.f};
  f32x4 acc1 = {0.f,0.f,0.f,0.f};
#pragma unroll
  for (int ks = 0; ks < 4; ++ks){
    int ko = ks*32 + kg*8;
    bf16x8 ah  = *(const bf16x8*)(ah_p  + ko);
    bf16x8 al  = *(const bf16x8*)(al_p  + ko);
    bf16x8 wh0 = *(const bf16x8*)(wh0_p + ko);
    bf16x8 wl0 = *(const bf16x8*)(wl0_p + ko);
    bf16x8 wh1 = *(const bf16x8*)(wh1_p + ko);
    bf16x8 wl1 = *(const bf16x8*)(wl1_p + ko);
    acc0 = __builtin_amdgcn_mfma_f32_16x16x32_bf16(ah, wh0, acc0, 0, 0, 0);
    acc0 = __builtin_amdgcn_mfma_f32_16x16x32_bf16(ah, wl0, acc0, 0, 0, 0);
    acc0 = __builtin_amdgcn_mfma_f32_16x16x32_bf16(al, wh0, acc0, 0, 0, 0);
    acc1 = __builtin_amdgcn_mfma_f32_16x16x32_bf16(ah, wh1, acc1, 0, 0, 0);
    acc1 = __builtin_amdgcn_mfma_f32_16x16x32_bf16(ah, wl1, acc1, 0, 0, 0);
    acc1 = __builtin_amdgcn_mfma_f32_16x16x32_bf16(al, wh1, acc1, 0, 0, 0);
  }

  // node->graph map
  int g0 = batch[n0];
  int nodebatch[4];
#pragma unroll
  for (int r2 = 0; r2 < 4; ++r2){
    int node = n0 + w*16 + kg*4 + r2;
    nodebatch[r2] = (node < N) ? batch[node] : -1;
  }

  // ---- epilogue: accumulate into LDS window, then flush ----
  __syncthreads();                 // plL zeroed visible
#pragma unroll
  for (int ft = 0; ft < 2; ++ft){
    f32x4 a = ft ? acc1 : acc0;
    int fl = ft*16 + row;           // local f in [0,32)
    int gf = fb*32 + fl;
    if (gf < 200){
      float bias = b2[gf];
      float s = 0.f;
      int gprev = -1;
#pragma unroll
      for (int r2 = 0; r2 < 4; ++r2){
        int gg = nodebatch[r2];
        if (gg >= 0){
          if (gg != gprev){
            if (gprev >= 0){
              int dg = gprev - g0;
              if (dg < 8) atomicAdd(&plL[dg*32 + fl], s);
              else        atomicAdd(&pooled[(size_t)gprev*200 + gf], s);
            }
            gprev = gg; s = 0.f;
          }
          s += silu_f(a[r2] + bias);
        }
      }
      if (gprev >= 0){
        int dg = gprev - g0;
        if (dg < 8) atomicAdd(&plL[dg*32 + fl], s);
        else        atomicAdd(&pooled[(size_t)gprev*200 + gf], s);
      }
    }
  }
  __syncthreads();
  for (int i2 = tid; i2 < 256; i2 += 128){
    float v = plL[i2];
    if (v != 0.f){
      int r2 = i2 >> 5, f = i2 & 31;
      int gf = fb*32 + f;
      if (gf < 200) atomicAdd(&pooled[(size_t)(g0+r2)*200 + gf], v);
    }
  }
}

// ---------- head: mean finalize + MLP, one block per graph ----------
__global__ __launch_bounds__(256) void k_head(const float* __restrict__ pooled, const int* __restrict__ batch,
                       const float* __restrict__ W3, const float* __restrict__ b3,
                       const float* __restrict__ W4, const float* __restrict__ b4,
                       float* __restrict__ out, int N){
  __shared__ float pl[200];
  __shared__ float h3[100];
  int g = blockIdx.x; int tid = threadIdx.x;
  int lo=0, hi=N;
  while (lo<hi){ int m=(lo+hi)>>1; if (batch[m] < g) lo=m+1; else hi=m; }
  int s = lo;
  hi=N;
  while (lo<hi){ int m=(lo+hi)>>1; if (batch[m] < g+1) lo=m+1; else hi=m; }
  int e = lo;
  float inv = (e>s) ? 1.0f/(float)(e-s) : 0.0f;
  if (tid < 200) pl[tid] = pooled[(size_t)g*200 + tid] * inv;
  __syncthreads();
  if (tid < 100){
    float acc = b3[tid];
    for (int k=0;k<200;++k) acc += pl[k]*W3[k*100+tid];
    h3[tid] = silu_f(acc);
  }
  __syncthreads();
  if (tid < WF){
    float p = 0.f;
    if (tid < 100)      p  = h3[tid]     * W4[tid];
    if (tid + 64 < 100) p += h3[tid+64]  * W4[tid+64];
#pragma unroll
    for (int off=32; off; off>>=1) p += __shfl_down(p, off);
    if (tid==0) out[g] = p + b4[0];
  }
}

extern "C" void kernel_launch(void* const* d_in, const int* in_sizes, int n_in,
                              void* d_out, int out_size, void* d_ws, size_t ws_size,
                              hipStream_t stream){
  const float* x  = (const float*)d_in[0];
  const int*   ei = (const int*)  d_in[1];
  const int* batch= (const int*)  d_in[2];
  const float* W1 = (const float*)d_in[4];
  const float* b1 = (const float*)d_in[5];
  const float* W2 = (const float*)d_in[6];
  const float* b2 = (const float*)d_in[7];
  const float* W3 = (const float*)d_in[8];
  const float* b3 = (const float*)d_in[9];
  const float* W4 = (const float*)d_in[10];
  const float* b4 = (const float*)d_in[11];
  float* out = (float*)d_out;

  int N = in_sizes[0]/3;
  int E = in_sizes[1]/2;
  int G = out_size;
  const int* src = ei;
  const int* dst = ei + E;
  int NP = ((N + 63)/64)*64;   // padded rows for mm2 tile overrun

  char* base = (char*)d_ws; size_t off = 0;
  auto alloc = [&](size_t bytes)->void*{
    void* p = base + off;
    off = (off + bytes + 255) & ~(size_t)255;
    return p;
  };
  // zero-init group first (single memset): cnt, pooled
  int*   cnt      = (int*)  alloc((size_t)N*4);
  float* pooled   = (float*)alloc((size_t)G*200*4);
  size_t zbytes   = off;
  int*   rowstart = (int*)  alloc((size_t)(N+1)*4);
  int*   cursor   = (int*)  alloc((size_t)N*4);
  int*   bsum     = (int*)  alloc(4096);
  int*   colsrc   = (int*)  alloc((size_t)E*4);
  float4* dxp     = (float4*)alloc((size_t)N*16);
  float4* z1      = (float4*)alloc((size_t)N*16);
  unsigned short* a2h = (unsigned short*)alloc((size_t)NP*128*2);
  unsigned short* a2l = (unsigned short*)alloc((size_t)NP*128*2);
  unsigned short* w2th = (unsigned short*)alloc((size_t)224*128*2);
  unsigned short* w2tl = (unsigned short*)alloc((size_t)224*128*2);
  (void)ws_size; (void)n_in;

  hipMemsetAsync(base, 0, zbytes, stream);
  int gE = (E+255)/256;
  int gW = (224*128+255)/256;
  k_count_wconv<<<gE+gW,256,0,stream>>>(dst, cnt, E, W2, w2th, w2tl, gE);
  int nb = (N+2047)/2048;
  k_scan1<<<nb,256,0,stream>>>(cnt, rowstart, bsum, N);
  k_scan3<<<(N+255)/256,256,0,stream>>>(bsum, cnt, x, rowstart, cursor, dxp, N, E, nb);
  k_fill<<<gE,256,0,stream>>>(src, dst, cursor, colsrc, E);
  k_z1<<<(N+255)/256,256,0,stream>>>(dxp, rowstart, colsrc, z1, N);
  k_agg2f<<<(N+7)/8,256,0,stream>>>(z1, rowstart, colsrc, W1, b1, a2h, a2l, N);
  int nwg = (N+31)/32;
  int total = nwg * 7;
  k_mm2<<<total,128,0,stream>>>(a2h, a2l, w2th, w2tl, b2, batch, pooled, N, total);
  k_head<<<G,256,0,stream>>>(pooled, batch, W3, b3, W4, b4, out, N);
}

// Round 24
// 167.751 us; speedup vs baseline: 1.0329x; 1.0329x over previous
//
#include <hip/hip_runtime.h>
#include <math.h>

#define WF 64

// hardware-native silu: v_exp_f32 (2^x) + v_rcp_f32 — ~5 VALU ops, ~1ulp
__device__ __forceinline__ float silu_f(float v){
  float e = __builtin_amdgcn_exp2f(v * -1.44269504088896340736f);
  return v * __builtin_amdgcn_rcpf(1.0f + e);
}

typedef __attribute__((ext_vector_type(8))) short bf16x8;
typedef __attribute__((ext_vector_type(4))) float f32x4;

__device__ __forceinline__ void bf16split(float v, unsigned short& h, unsigned short& l){
  unsigned int b = __float_as_uint(v);
  unsigned int hh = (b + 0x8000u) >> 16;
  float hf = __uint_as_float(hh << 16);
  float lo = v - hf;
  unsigned int bl = __float_as_uint(lo);
  h = (unsigned short)hh;
  l = (unsigned short)((bl + 0x8000u) >> 16);
}

// ---------- CSR count + W2 conversion (merged grids; independent work) ----------
__global__ __launch_bounds__(256) void k_count_wconv(const int* __restrict__ dst, int* __restrict__ cnt, int E,
                       const float* __restrict__ W2,
                       unsigned short* __restrict__ w2th, unsigned short* __restrict__ w2tl,
                       int nCountBlocks){
  int b = blockIdx.x;
  if (b < nCountBlocks){
    int e = b*256 + threadIdx.x;
    if (e < E) atomicAdd(&cnt[dst[e]], 1);
  } else {
    int idx = (b - nCountBlocks)*256 + threadIdx.x;
    if (idx < 224*128){
      int f = idx >> 7, k = idx & 127;
      float v = (f < 200 && k < 100) ? W2[(size_t)k*200 + f] : 0.f;
      unsigned short h, l;
      bf16split(v, h, l);
      w2th[idx] = h;
      w2tl[idx] = l;
    }
  }
}

// block-local exclusive scan over chunks of 2048 (256 thr x 8 items)
__global__ __launch_bounds__(256) void k_scan1(const int* __restrict__ cnt, int* __restrict__ rowstart, int* __restrict__ bsum, int N){
  __shared__ int s[256];
  int tid = threadIdx.x;
  int base = blockIdx.x*2048 + tid*8;
  int loc[8]; int tsum = 0;
#pragma unroll
  for (int j=0;j<8;++j){ int idx=base+j; int v = (idx<N)?cnt[idx]:0; loc[j]=tsum; tsum+=v; }
  s[tid]=tsum; __syncthreads();
  for (int off=1; off<256; off<<=1){
    int v = (tid>=off)? s[tid-off] : 0;
    __syncthreads();
    s[tid] += v;
    __syncthreads();
  }
  int texc = s[tid] - tsum;
  if (tid==255) bsum[blockIdx.x] = s[255];
#pragma unroll
  for (int j=0;j<8;++j){ int idx=base+j; if (idx<N) rowstart[idx] = texc + loc[j]; }
}

// scan3: adds block prefix (from bsum), writes cursor and dxp = {di, di*x}
__global__ __launch_bounds__(256) void k_scan3(const int* __restrict__ bsum, const int* __restrict__ cnt,
                        const float* __restrict__ x,
                        int* __restrict__ rowstart, int* __restrict__ cursor,
                        float4* __restrict__ dxp,
                        int N, int E, int nb){
  __shared__ int boffs;
  int tid = threadIdx.x;
  int b = (blockIdx.x*blockDim.x) >> 11;   // uniform within block (256 <= 2048)
  if (tid < WF){
    int v = (tid < nb && tid < b) ? bsum[tid] : 0;
#pragma unroll
    for (int off=32; off; off>>=1) v += __shfl_down(v, off);
    if (tid==0) boffs = v;
  }
  __syncthreads();
  int idx = blockIdx.x*blockDim.x + tid;
  if (idx < N){
    int v = rowstart[idx] + boffs;
    rowstart[idx]=v; cursor[idx]=v;
    float di = rsqrtf((float)(cnt[idx]+1));   // +1 self-loop
    float4 o;
    o.x = di;
    o.y = di*x[3*idx+0];
    o.z = di*x[3*idx+1];
    o.w = di*x[3*idx+2];
    dxp[idx] = o;
  }
  if (idx==0) rowstart[N]=E;
}

// fill CSR: minimum scatter — one 4B colsrc write + cursor atomic per edge
__global__ __launch_bounds__(256) void k_fill(const int* __restrict__ src, const int* __restrict__ dst,
                       int* __restrict__ cursor, int* __restrict__ colsrc, int E){
  int e = blockIdx.x*blockDim.x + threadIdx.x;
  if (e < E){
    int d = dst[e];
    int pos = atomicAdd(&cursor[d], 1);
    colsrc[pos] = src[e];
  }
}

// ---------- z1: layer-1 aggregated input (3-dim CSR walk over dxp) ----------
__global__ __launch_bounds__(256) void k_z1(const float4* __restrict__ dxp,
                     const int* __restrict__ rowstart, const int* __restrict__ colsrc,
                     float4* __restrict__ z1, int N){
  int i = blockIdx.x*blockDim.x + threadIdx.x;
  if (i >= N) return;
  float4 self = dxp[i];
  float di = self.x;
  float sx = self.y, sy = self.z, sz = self.w;
  int jb = rowstart[i], je = rowstart[i+1];
  int j = jb;
  for (; j+3 < je; j += 4){
    float4 r0 = dxp[colsrc[j]];
    float4 r1 = dxp[colsrc[j+1]];
    float4 r2 = dxp[colsrc[j+2]];
    float4 r3 = dxp[colsrc[j+3]];
    sx += (r0.y + r1.y) + (r2.y + r3.y);
    sy += (r0.z + r1.z) + (r2.z + r3.z);
    sz += (r0.w + r1.w) + (r2.w + r3.w);
  }
  for (; j < je; ++j){
    float4 r = dxp[colsrc[j]];
    sx += r.y; sy += r.z; sz += r.w;
  }
  float4 o;
  o.x = di;
  o.y = di*sx; o.z = di*sy; o.w = di*sz;
  z1[i] = o;
}

// ---------- FUSED layer-1 transform + layer-2 aggregation -> bf16 planes ----------
// HALF-WAVE per node; 4x-unrolled neighbor loop for load ILP.
__global__ __launch_bounds__(256) void k_agg2f(const float4* __restrict__ z1,
                       const int* __restrict__ rowstart, const int* __restrict__ colsrc,
                       const float* __restrict__ W1, const float* __restrict__ b1,
                       unsigned short* __restrict__ a2h, unsigned short* __restrict__ a2l, int N){
  __shared__ float w[300];
  __shared__ float bb[100];
  int tid = threadIdx.x;
  for (int t=tid; t<300; t+=256) w[t]=W1[t];
  for (int t=tid; t<100; t+=256) bb[t]=b1[t];
  __syncthreads();

  int node = blockIdx.x*8 + (tid >> 5);
  int lane = tid & 31;
  if (node >= N) return;
  if (lane >= 25){
    int ko = 100 + (lane-25)*4;
    ushort4 z = make_ushort4(0,0,0,0);
    *(ushort4*)(a2h + (size_t)node*128 + ko) = z;
    *(ushort4*)(a2l + (size_t)node*128 + ko) = z;
    return;
  }
  int f0 = lane*4;
  float w0[4], w1[4], w2[4], b[4];
#pragma unroll
  for (int j=0;j<4;++j){
    w0[j] = w[f0+j]; w1[j] = w[100+f0+j]; w2[j] = w[200+f0+j]; b[j] = bb[f0+j];
  }

  float4 zn = z1[node];
  float din = zn.x;
  float acc[4];
#pragma unroll
  for (int j=0;j<4;++j){
    float h = silu_f(zn.y*w0[j] + zn.z*w1[j] + zn.w*w2[j] + b[j]);
    acc[j] = din*h;
  }
  int jb = rowstart[node], je = rowstart[node+1];
  int e = jb;
  for (; e+3 < je; e += 4){
    float4 zu0 = z1[colsrc[e]];
    float4 zu1 = z1[colsrc[e+1]];
    float4 zu2 = z1[colsrc[e+2]];
    float4 zu3 = z1[colsrc[e+3]];
#pragma unroll
    for (int j=0;j<4;++j){
      float h0 = silu_f(zu0.y*w0[j] + zu0.z*w1[j] + zu0.w*w2[j] + b[j]);
      float h1v = silu_f(zu1.y*w0[j] + zu1.z*w1[j] + zu1.w*w2[j] + b[j]);
      float h2v = silu_f(zu2.y*w0[j] + zu2.z*w1[j] + zu2.w*w2[j] + b[j]);
      float h3v = silu_f(zu3.y*w0[j] + zu3.z*w1[j] + zu3.w*w2[j] + b[j]);
      acc[j] += (zu0.x*h0 + zu1.x*h1v) + (zu2.x*h2v + zu3.x*h3v);
    }
  }
  for (; e < je; ++e){
    float4 zu = z1[colsrc[e]];
#pragma unroll
    for (int j=0;j<4;++j){
      float h = silu_f(zu.y*w0[j] + zu.z*w1[j] + zu.w*w2[j] + b[j]);
      acc[j] += zu.x*h;
    }
  }
  ushort4 h4, l4;
  bf16split(din*acc[0], h4.x, l4.x);
  bf16split(din*acc[1], h4.y, l4.y);
  bf16split(din*acc[2], h4.z, l4.z);
  bf16split(din*acc[3], h4.w, l4.w);
  *(ushort4*)(a2h + (size_t)node*128 + f0) = h4;
  *(ushort4*)(a2l + (size_t)node*128 + f0) = l4;
}

// ---------- layer 2 matmul via split-bf16 MFMA + fused mean-pool ----------
// R21 structure + 2-WAY FB SPLIT (blockIdx.y: 0 -> fb 0..3, 1 -> fb 4..6).
__global__ __launch_bounds__(128) void k_mm2(const unsigned short* __restrict__ a2h,
                      const unsigned short* __restrict__ a2l,
                      const unsigned short* __restrict__ w2th,
                      const unsigned short* __restrict__ w2tl,
                      const float* __restrict__ b2, const int* __restrict__ batch,
                      float* __restrict__ pooled, int N, int nwg){
  __shared__ float plL[256];
  int tid = threadIdx.x;
  int l = tid & 63, w = tid >> 6;   // w in {0,1}
  // bijective XCD swizzle on x
  int orig = blockIdx.x;
  int q = nwg >> 3, r = nwg & 7;
  int xcd = orig % 8, rk = orig / 8;
  int bid = (xcd < r) ? (xcd*(q+1) + rk) : (r*(q+1) + (xcd-r)*q + rk);
  int n0 = bid * 32;
  int row = l & 15;
  int kg  = l >> 4;
  int fb0 = blockIdx.y ? 4 : 0;
  int fb1 = blockIdx.y ? 7 : 4;

  const unsigned short* ah_p = a2h + (size_t)(n0 + w*16 + row)*128;
  const unsigned short* al_p = a2l + (size_t)(n0 + w*16 + row)*128;

  bf16x8 ahf[4], alf[4];
#pragma unroll
  for (int ks = 0; ks < 4; ++ks){
    int ko = ks*32 + kg*8;
    ahf[ks] = *(const bf16x8*)(ah_p + ko);
    alf[ks] = *(const bf16x8*)(al_p + ko);
  }

  // hoisted per-thread node->graph map (constant across fb loop)
  int g0 = batch[n0];
  int nodebatch[4];
#pragma unroll
  for (int r2 = 0; r2 < 4; ++r2){
    int node = n0 + w*16 + kg*4 + r2;
    nodebatch[r2] = (node < N) ? batch[node] : -1;
  }

  // zero plL once (first epilogue's entry barrier publishes it)
  for (int idx = tid; idx < 256; idx += 128) plL[idx] = 0.f;

  // prefetch W group ks=0 of first fb
  int kof = kg*8;
  bf16x8 pwh0 = *(const bf16x8*)(w2th + (size_t)(fb0*32 + row     )*128 + kof);
  bf16x8 pwl0 = *(const bf16x8*)(w2tl + (size_t)(fb0*32 + row     )*128 + kof);
  bf16x8 pwh1 = *(const bf16x8*)(w2th + (size_t)(fb0*32 + 16 + row)*128 + kof);
  bf16x8 pwl1 = *(const bf16x8*)(w2tl + (size_t)(fb0*32 + 16 + row)*128 + kof);

  for (int fb = fb0; fb < fb1; ++fb){
    int gf0 = fb*32 + row, gf1 = gf0 + 16;
    const unsigned short* wh0_p = w2th + (size_t)gf0*128;
    const unsigned short* wl0_p = w2tl + (size_t)gf0*128;
    const unsigned short* wh1_p = w2th + (size_t)gf1*128;
    const unsigned short* wl1_p = w2tl + (size_t)gf1*128;

    f32x4 acc0 = {0.f,0.f,0.f,0.f};
    f32x4 acc1 = {0.f,0.f,0.f,0.f};
    // ks = 0 from prefetched registers
    acc0 = __builtin_amdgcn_mfma_f32_16x16x32_bf16(ahf[0], pwh0, acc0, 0, 0, 0);
    acc0 = __builtin_amdgcn_mfma_f32_16x16x32_bf16(ahf[0], pwl0, acc0, 0, 0, 0);
    acc0 = __builtin_amdgcn_mfma_f32_16x16x32_bf16(alf[0], pwh0, acc0, 0, 0, 0);
    acc1 = __builtin_amdgcn_mfma_f32_16x16x32_bf16(ahf[0], pwh1, acc1, 0, 0, 0);
    acc1 = __builtin_amdgcn_mfma_f32_16x16x32_bf16(ahf[0], pwl1, acc1, 0, 0, 0);
    acc1 = __builtin_amdgcn_mfma_f32_16x16x32_bf16(alf[0], pwh1, acc1, 0, 0, 0);
#pragma unroll
    for (int ks = 1; ks < 4; ++ks){
      int ko = ks*32 + kg*8;
      bf16x8 wh0 = *(const bf16x8*)(wh0_p + ko);
      bf16x8 wl0 = *(const bf16x8*)(wl0_p + ko);
      bf16x8 wh1 = *(const bf16x8*)(wh1_p + ko);
      bf16x8 wl1 = *(const bf16x8*)(wl1_p + ko);
      acc0 = __builtin_amdgcn_mfma_f32_16x16x32_bf16(ahf[ks], wh0, acc0, 0, 0, 0);
      acc0 = __builtin_amdgcn_mfma_f32_16x16x32_bf16(ahf[ks], wl0, acc0, 0, 0, 0);
      acc0 = __builtin_amdgcn_mfma_f32_16x16x32_bf16(alf[ks], wh0, acc0, 0, 0, 0);
      acc1 = __builtin_amdgcn_mfma_f32_16x16x32_bf16(ahf[ks], wh1, acc1, 0, 0, 0);
      acc1 = __builtin_amdgcn_mfma_f32_16x16x32_bf16(ahf[ks], wl1, acc1, 0, 0, 0);
      acc1 = __builtin_amdgcn_mfma_f32_16x16x32_bf16(alf[ks], wh1, acc1, 0, 0, 0);
    }

    // prefetch next fb's W group ks=0 — latency hides under the epilogue
    if (fb+1 < fb1){
      int ngf0 = (fb+1)*32 + row, ngf1 = ngf0 + 16;
      pwh0 = *(const bf16x8*)(w2th + (size_t)ngf0*128 + kof);
      pwl0 = *(const bf16x8*)(w2tl + (size_t)ngf0*128 + kof);
      pwh1 = *(const bf16x8*)(w2th + (size_t)ngf1*128 + kof);
      pwl1 = *(const bf16x8*)(w2tl + (size_t)ngf1*128 + kof);
    }

    // ---- epilogue: 2 barriers (accumulate window, then flush+zero) ----
    __syncthreads();                 // plL zeroed & previous flush done
#pragma unroll
    for (int ft = 0; ft < 2; ++ft){
      f32x4 a = ft ? acc1 : acc0;
      int fl = ft*16 + row;           // local f in [0,32)
      int gf = fb*32 + fl;
      if (gf < 200){
        float bias = b2[gf];
        float s = 0.f;
        int gprev = -1;
#pragma unroll
        for (int r2 = 0; r2 < 4; ++r2){
          int g = nodebatch[r2];
          if (g >= 0){
            if (g != gprev){
              if (gprev >= 0){
                int dg = gprev - g0;
                if (dg < 8) atomicAdd(&plL[dg*32 + fl], s);
                else        atomicAdd(&pooled[(size_t)gprev*200 + gf], s);
              }
              gprev = g; s = 0.f;
            }
            s += silu_f(a[r2] + bias);
          }
        }
        if (gprev >= 0){
          int dg = gprev - g0;
          if (dg < 8) atomicAdd(&plL[dg*32 + fl], s);
          else        atomicAdd(&pooled[(size_t)gprev*200 + gf], s);
        }
      }
    }
    __syncthreads();
    // flush + zero in one pass; next fb's MFMAs overlap these atomics
    for (int idx = tid; idx < 256; idx += 128){
      float v = plL[idx];
      plL[idx] = 0.f;
      if (v != 0.f){
        int r2 = idx >> 5, f = idx & 31;
        int gf = fb*32 + f;
        if (gf < 200) atomicAdd(&pooled[(size_t)(g0+r2)*200 + gf], v);
      }
    }
  }
}

// ---------- head: mean finalize + MLP, one block per graph ----------
__global__ __launch_bounds__(256) void k_head(const float* __restrict__ pooled, const int* __restrict__ batch,
                       const float* __restrict__ W3, const float* __restrict__ b3,
                       const float* __restrict__ W4, const float* __restrict__ b4,
                       float* __restrict__ out, int N){
  __shared__ float pl[200];
  __shared__ float h3[100];
  int g = blockIdx.x; int tid = threadIdx.x;
  int lo=0, hi=N;
  while (lo<hi){ int m=(lo+hi)>>1; if (batch[m] < g) lo=m+1; else hi=m; }
  int s = lo;
  hi=N;
  while (lo<hi){ int m=(lo+hi)>>1; if (batch[m] < g+1) lo=m+1; else hi=m; }
  int e = lo;
  float inv = (e>s) ? 1.0f/(float)(e-s) : 0.0f;
  if (tid < 200) pl[tid] = pooled[(size_t)g*200 + tid] * inv;
  __syncthreads();
  if (tid < 100){
    float acc = b3[tid];
    for (int k=0;k<200;++k) acc += pl[k]*W3[k*100+tid];
    h3[tid] = silu_f(acc);
  }
  __syncthreads();
  if (tid < WF){
    float p = 0.f;
    if (tid < 100)      p  = h3[tid]     * W4[tid];
    if (tid + 64 < 100) p += h3[tid+64]  * W4[tid+64];
#pragma unroll
    for (int off=32; off; off>>=1) p += __shfl_down(p, off);
    if (tid==0) out[g] = p + b4[0];
  }
}

extern "C" void kernel_launch(void* const* d_in, const int* in_sizes, int n_in,
                              void* d_out, int out_size, void* d_ws, size_t ws_size,
                              hipStream_t stream){
  const float* x  = (const float*)d_in[0];
  const int*   ei = (const int*)  d_in[1];
  const int* batch= (const int*)  d_in[2];
  const float* W1 = (const float*)d_in[4];
  const float* b1 = (const float*)d_in[5];
  const float* W2 = (const float*)d_in[6];
  const float* b2 = (const float*)d_in[7];
  const float* W3 = (const float*)d_in[8];
  const float* b3 = (const float*)d_in[9];
  const float* W4 = (const float*)d_in[10];
  const float* b4 = (const float*)d_in[11];
  float* out = (float*)d_out;

  int N = in_sizes[0]/3;
  int E = in_sizes[1]/2;
  int G = out_size;
  const int* src = ei;
  const int* dst = ei + E;
  int NP = ((N + 63)/64)*64;   // padded rows for mm2 tile overrun

  char* base = (char*)d_ws; size_t off = 0;
  auto alloc = [&](size_t bytes)->void*{
    void* p = base + off;
    off = (off + bytes + 255) & ~(size_t)255;
    return p;
  };
  // zero-init group first (single memset): cnt, pooled
  int*   cnt      = (int*)  alloc((size_t)N*4);
  float* pooled   = (float*)alloc((size_t)G*200*4);
  size_t zbytes   = off;
  int*   rowstart = (int*)  alloc((size_t)(N+1)*4);
  int*   cursor   = (int*)  alloc((size_t)N*4);
  int*   bsum     = (int*)  alloc(4096);
  int*   colsrc   = (int*)  alloc((size_t)E*4);
  float4* dxp     = (float4*)alloc((size_t)N*16);
  float4* z1      = (float4*)alloc((size_t)N*16);
  unsigned short* a2h = (unsigned short*)alloc((size_t)NP*128*2);
  unsigned short* a2l = (unsigned short*)alloc((size_t)NP*128*2);
  unsigned short* w2th = (unsigned short*)alloc((size_t)224*128*2);
  unsigned short* w2tl = (unsigned short*)alloc((size_t)224*128*2);
  (void)ws_size; (void)n_in;

  hipMemsetAsync(base, 0, zbytes, stream);
  int gE = (E+255)/256;
  int gW = (224*128+255)/256;
  k_count_wconv<<<gE+gW,256,0,stream>>>(dst, cnt, E, W2, w2th, w2tl, gE);
  int nb = (N+2047)/2048;
  k_scan1<<<nb,256,0,stream>>>(cnt, rowstart, bsum, N);
  k_scan3<<<(N+255)/256,256,0,stream>>>(bsum, cnt, x, rowstart, cursor, dxp, N, E, nb);
  k_fill<<<gE,256,0,stream>>>(src, dst, cursor, colsrc, E);
  k_z1<<<(N+255)/256,256,0,stream>>>(dxp, rowstart, colsrc, z1, N);
  k_agg2f<<<(N+7)/8,256,0,stream>>>(z1, rowstart, colsrc, W1, b1, a2h, a2l, N);
  int nwg = (N+31)/32;
  dim3 gmm(nwg, 2);
  k_mm2<<<gmm,128,0,stream>>>(a2h, a2l, w2th, w2tl, b2, batch, pooled, N, nwg);
  k_head<<<G,256,0,stream>>>(pooled, batch, W3, b3, W4, b4, out, N);
}

// Round 25
// 167.245 us; speedup vs baseline: 1.0360x; 1.0030x over previous
//
#include <hip/hip_runtime.h>
#include <math.h>

#define WF 64

// hardware-native silu: v_exp_f32 (2^x) + v_rcp_f32 — ~5 VALU ops, ~1ulp
__device__ __forceinline__ float silu_f(float v){
  float e = __builtin_amdgcn_exp2f(v * -1.44269504088896340736f);
  return v * __builtin_amdgcn_rcpf(1.0f + e);
}

typedef __attribute__((ext_vector_type(8))) short bf16x8;
typedef __attribute__((ext_vector_type(4))) float f32x4;

__device__ __forceinline__ void bf16split(float v, unsigned short& h, unsigned short& l){
  unsigned int b = __float_as_uint(v);
  unsigned int hh = (b + 0x8000u) >> 16;
  float hf = __uint_as_float(hh << 16);
  float lo = v - hf;
  unsigned int bl = __float_as_uint(lo);
  h = (unsigned short)hh;
  l = (unsigned short)((bl + 0x8000u) >> 16);
}

// ---------- CSR count + W2 conversion + pooled zeroing (merged independent work) ----------
__global__ __launch_bounds__(256) void k_count_wconv(const int* __restrict__ dst, int* __restrict__ cnt, int E,
                       const float* __restrict__ W2,
                       unsigned short* __restrict__ w2th, unsigned short* __restrict__ w2tl,
                       float* __restrict__ pooled, int poolN,
                       int nCountBlocks, int nWBlocks){
  int b = blockIdx.x;
  if (b < nCountBlocks){
    int e = b*256 + threadIdx.x;
    if (e < E) atomicAdd(&cnt[dst[e]], 1);
  } else if (b < nCountBlocks + nWBlocks){
    int idx = (b - nCountBlocks)*256 + threadIdx.x;
    if (idx < 224*128){
      int f = idx >> 7, k = idx & 127;
      float v = (f < 200 && k < 100) ? W2[(size_t)k*200 + f] : 0.f;
      unsigned short h, l;
      bf16split(v, h, l);
      w2th[idx] = h;
      w2tl[idx] = l;
    }
  } else {
    // zero pooled (untouched until k_mm2, 4 launches later — no race)
    int idx = (b - nCountBlocks - nWBlocks)*256 + threadIdx.x;
    if (idx < poolN) pooled[idx] = 0.f;
  }
}

// block-local exclusive scan over chunks of 2048 (256 thr x 8 items)
__global__ __launch_bounds__(256) void k_scan1(const int* __restrict__ cnt, int* __restrict__ rowstart, int* __restrict__ bsum, int N){
  __shared__ int s[256];
  int tid = threadIdx.x;
  int base = blockIdx.x*2048 + tid*8;
  int loc[8]; int tsum = 0;
#pragma unroll
  for (int j=0;j<8;++j){ int idx=base+j; int v = (idx<N)?cnt[idx]:0; loc[j]=tsum; tsum+=v; }
  s[tid]=tsum; __syncthreads();
  for (int off=1; off<256; off<<=1){
    int v = (tid>=off)? s[tid-off] : 0;
    __syncthreads();
    s[tid] += v;
    __syncthreads();
  }
  int texc = s[tid] - tsum;
  if (tid==255) bsum[blockIdx.x] = s[255];
#pragma unroll
  for (int j=0;j<8;++j){ int idx=base+j; if (idx<N) rowstart[idx] = texc + loc[j]; }
}

// scan3: adds block prefix (from bsum), writes cursor and dxp = {di, di*x}
__global__ __launch_bounds__(256) void k_scan3(const int* __restrict__ bsum, const int* __restrict__ cnt,
                        const float* __restrict__ x,
                        int* __restrict__ rowstart, int* __restrict__ cursor,
                        float4* __restrict__ dxp,
                        int N, int E, int nb){
  __shared__ int boffs;
  int tid = threadIdx.x;
  int b = (blockIdx.x*blockDim.x) >> 11;   // uniform within block (256 <= 2048)
  if (tid < WF){
    int v = (tid < nb && tid < b) ? bsum[tid] : 0;
#pragma unroll
    for (int off=32; off; off>>=1) v += __shfl_down(v, off);
    if (tid==0) boffs = v;
  }
  __syncthreads();
  int idx = blockIdx.x*blockDim.x + tid;
  if (idx < N){
    int v = rowstart[idx] + boffs;
    rowstart[idx]=v; cursor[idx]=v;
    float di = rsqrtf((float)(cnt[idx]+1));   // +1 self-loop
    float4 o;
    o.x = di;
    o.y = di*x[3*idx+0];
    o.z = di*x[3*idx+1];
    o.w = di*x[3*idx+2];
    dxp[idx] = o;
  }
  if (idx==0) rowstart[N]=E;
}

// fill CSR: minimum scatter — one 4B colsrc write + cursor atomic per edge
__global__ __launch_bounds__(256) void k_fill(const int* __restrict__ src, const int* __restrict__ dst,
                       int* __restrict__ cursor, int* __restrict__ colsrc, int E){
  int e = blockIdx.x*blockDim.x + threadIdx.x;
  if (e < E){
    int d = dst[e];
    int pos = atomicAdd(&cursor[d], 1);
    colsrc[pos] = src[e];
  }
}

// ---------- z1: layer-1 aggregated input (3-dim CSR walk over dxp) ----------
__global__ __launch_bounds__(256) void k_z1(const float4* __restrict__ dxp,
                     const int* __restrict__ rowstart, const int* __restrict__ colsrc,
                     float4* __restrict__ z1, int N){
  int i = blockIdx.x*blockDim.x + threadIdx.x;
  if (i >= N) return;
  float4 self = dxp[i];
  float di = self.x;
  float sx = self.y, sy = self.z, sz = self.w;
  int jb = rowstart[i], je = rowstart[i+1];
  int j = jb;
  for (; j+3 < je; j += 4){
    float4 r0 = dxp[colsrc[j]];
    float4 r1 = dxp[colsrc[j+1]];
    float4 r2 = dxp[colsrc[j+2]];
    float4 r3 = dxp[colsrc[j+3]];
    sx += (r0.y + r1.y) + (r2.y + r3.y);
    sy += (r0.z + r1.z) + (r2.z + r3.z);
    sz += (r0.w + r1.w) + (r2.w + r3.w);
  }
  for (; j < je; ++j){
    float4 r = dxp[colsrc[j]];
    sx += r.y; sy += r.z; sz += r.w;
  }
  float4 o;
  o.x = di;
  o.y = di*sx; o.z = di*sy; o.w = di*sz;
  z1[i] = o;
}

// ---------- FUSED layer-1 transform + layer-2 aggregation -> bf16 planes ----------
// HALF-WAVE per node; 4x-unrolled neighbor loop for load ILP.
__global__ __launch_bounds__(256) void k_agg2f(const float4* __restrict__ z1,
                       const int* __restrict__ rowstart, const int* __restrict__ colsrc,
                       const float* __restrict__ W1, const float* __restrict__ b1,
                       unsigned short* __restrict__ a2h, unsigned short* __restrict__ a2l, int N){
  __shared__ float w[300];
  __shared__ float bb[100];
  int tid = threadIdx.x;
  for (int t=tid; t<300; t+=256) w[t]=W1[t];
  for (int t=tid; t<100; t+=256) bb[t]=b1[t];
  __syncthreads();

  int node = blockIdx.x*8 + (tid >> 5);
  int lane = tid & 31;
  if (node >= N) return;
  if (lane >= 25){
    int ko = 100 + (lane-25)*4;
    ushort4 z = make_ushort4(0,0,0,0);
    *(ushort4*)(a2h + (size_t)node*128 + ko) = z;
    *(ushort4*)(a2l + (size_t)node*128 + ko) = z;
    return;
  }
  int f0 = lane*4;
  float w0[4], w1[4], w2[4], b[4];
#pragma unroll
  for (int j=0;j<4;++j){
    w0[j] = w[f0+j]; w1[j] = w[100+f0+j]; w2[j] = w[200+f0+j]; b[j] = bb[f0+j];
  }

  float4 zn = z1[node];
  float din = zn.x;
  float acc[4];
#pragma unroll
  for (int j=0;j<4;++j){
    float h = silu_f(zn.y*w0[j] + zn.z*w1[j] + zn.w*w2[j] + b[j]);
    acc[j] = din*h;
  }
  int jb = rowstart[node], je = rowstart[node+1];
  int e = jb;
  for (; e+3 < je; e += 4){
    float4 zu0 = z1[colsrc[e]];
    float4 zu1 = z1[colsrc[e+1]];
    float4 zu2 = z1[colsrc[e+2]];
    float4 zu3 = z1[colsrc[e+3]];
#pragma unroll
    for (int j=0;j<4;++j){
      float h0 = silu_f(zu0.y*w0[j] + zu0.z*w1[j] + zu0.w*w2[j] + b[j]);
      float h1v = silu_f(zu1.y*w0[j] + zu1.z*w1[j] + zu1.w*w2[j] + b[j]);
      float h2v = silu_f(zu2.y*w0[j] + zu2.z*w1[j] + zu2.w*w2[j] + b[j]);
      float h3v = silu_f(zu3.y*w0[j] + zu3.z*w1[j] + zu3.w*w2[j] + b[j]);
      acc[j] += (zu0.x*h0 + zu1.x*h1v) + (zu2.x*h2v + zu3.x*h3v);
    }
  }
  for (; e < je; ++e){
    float4 zu = z1[colsrc[e]];
#pragma unroll
    for (int j=0;j<4;++j){
      float h = silu_f(zu.y*w0[j] + zu.z*w1[j] + zu.w*w2[j] + b[j]);
      acc[j] += zu.x*h;
    }
  }
  ushort4 h4, l4;
  bf16split(din*acc[0], h4.x, l4.x);
  bf16split(din*acc[1], h4.y, l4.y);
  bf16split(din*acc[2], h4.z, l4.z);
  bf16split(din*acc[3], h4.w, l4.w);
  *(ushort4*)(a2h + (size_t)node*128 + f0) = h4;
  *(ushort4*)(a2l + (size_t)node*128 + f0) = l4;
}

// ---------- layer 2 matmul via split-bf16 MFMA + fused mean-pool ----------
// R22 structure: 2-WAY FB SPLIT (blockIdx.y: 0 -> fb 0..3, 1 -> fb 4..6),
// A frags in regs, W prefetch under epilogue, 2-barrier merged flush+zero.
__global__ __launch_bounds__(128) void k_mm2(const unsigned short* __restrict__ a2h,
                      const unsigned short* __restrict__ a2l,
                      const unsigned short* __restrict__ w2th,
                      const unsigned short* __restrict__ w2tl,
                      const float* __restrict__ b2, const int* __restrict__ batch,
                      float* __restrict__ pooled, int N, int nwg){
  __shared__ float plL[256];
  int tid = threadIdx.x;
  int l = tid & 63, w = tid >> 6;   // w in {0,1}
  // bijective XCD swizzle on x
  int orig = blockIdx.x;
  int q = nwg >> 3, r = nwg & 7;
  int xcd = orig % 8, rk = orig / 8;
  int bid = (xcd < r) ? (xcd*(q+1) + rk) : (r*(q+1) + (xcd-r)*q + rk);
  int n0 = bid * 32;
  int row = l & 15;
  int kg  = l >> 4;
  int fb0 = blockIdx.y ? 4 : 0;
  int fb1 = blockIdx.y ? 7 : 4;

  const unsigned short* ah_p = a2h + (size_t)(n0 + w*16 + row)*128;
  const unsigned short* al_p = a2l + (size_t)(n0 + w*16 + row)*128;

  bf16x8 ahf[4], alf[4];
#pragma unroll
  for (int ks = 0; ks < 4; ++ks){
    int ko = ks*32 + kg*8;
    ahf[ks] = *(const bf16x8*)(ah_p + ko);
    alf[ks] = *(const bf16x8*)(al_p + ko);
  }

  // hoisted per-thread node->graph map (constant across fb loop)
  int g0 = batch[n0];
  int nodebatch[4];
#pragma unroll
  for (int r2 = 0; r2 < 4; ++r2){
    int node = n0 + w*16 + kg*4 + r2;
    nodebatch[r2] = (node < N) ? batch[node] : -1;
  }

  // zero plL once (first epilogue's entry barrier publishes it)
  for (int idx = tid; idx < 256; idx += 128) plL[idx] = 0.f;

  // prefetch W group ks=0 of first fb
  int kof = kg*8;
  bf16x8 pwh0 = *(const bf16x8*)(w2th + (size_t)(fb0*32 + row     )*128 + kof);
  bf16x8 pwl0 = *(const bf16x8*)(w2tl + (size_t)(fb0*32 + row     )*128 + kof);
  bf16x8 pwh1 = *(const bf16x8*)(w2th + (size_t)(fb0*32 + 16 + row)*128 + kof);
  bf16x8 pwl1 = *(const bf16x8*)(w2tl + (size_t)(fb0*32 + 16 + row)*128 + kof);

  for (int fb = fb0; fb < fb1; ++fb){
    int gf0 = fb*32 + row, gf1 = gf0 + 16;
    const unsigned short* wh0_p = w2th + (size_t)gf0*128;
    const unsigned short* wl0_p = w2tl + (size_t)gf0*128;
    const unsigned short* wh1_p = w2th + (size_t)gf1*128;
    const unsigned short* wl1_p = w2tl + (size_t)gf1*128;

    f32x4 acc0 = {0.f,0.f,0.f,0.f};
    f32x4 acc1 = {0.f,0.f,0.f,0.f};
    // ks = 0 from prefetched registers
    acc0 = __builtin_amdgcn_mfma_f32_16x16x32_bf16(ahf[0], pwh0, acc0, 0, 0, 0);
    acc0 = __builtin_amdgcn_mfma_f32_16x16x32_bf16(ahf[0], pwl0, acc0, 0, 0, 0);
    acc0 = __builtin_amdgcn_mfma_f32_16x16x32_bf16(alf[0], pwh0, acc0, 0, 0, 0);
    acc1 = __builtin_amdgcn_mfma_f32_16x16x32_bf16(ahf[0], pwh1, acc1, 0, 0, 0);
    acc1 = __builtin_amdgcn_mfma_f32_16x16x32_bf16(ahf[0], pwl1, acc1, 0, 0, 0);
    acc1 = __builtin_amdgcn_mfma_f32_16x16x32_bf16(alf[0], pwh1, acc1, 0, 0, 0);
#pragma unroll
    for (int ks = 1; ks < 4; ++ks){
      int ko = ks*32 + kg*8;
      bf16x8 wh0 = *(const bf16x8*)(wh0_p + ko);
      bf16x8 wl0 = *(const bf16x8*)(wl0_p + ko);
      bf16x8 wh1 = *(const bf16x8*)(wh1_p + ko);
      bf16x8 wl1 = *(const bf16x8*)(wl1_p + ko);
      acc0 = __builtin_amdgcn_mfma_f32_16x16x32_bf16(ahf[ks], wh0, acc0, 0, 0, 0);
      acc0 = __builtin_amdgcn_mfma_f32_16x16x32_bf16(ahf[ks], wl0, acc0, 0, 0, 0);
      acc0 = __builtin_amdgcn_mfma_f32_16x16x32_bf16(alf[ks], wh0, acc0, 0, 0, 0);
      acc1 = __builtin_amdgcn_mfma_f32_16x16x32_bf16(ahf[ks], wh1, acc1, 0, 0, 0);
      acc1 = __builtin_amdgcn_mfma_f32_16x16x32_bf16(ahf[ks], wl1, acc1, 0, 0, 0);
      acc1 = __builtin_amdgcn_mfma_f32_16x16x32_bf16(alf[ks], wh1, acc1, 0, 0, 0);
    }

    // prefetch next fb's W group ks=0 — latency hides under the epilogue
    if (fb+1 < fb1){
      int ngf0 = (fb+1)*32 + row, ngf1 = ngf0 + 16;
      pwh0 = *(const bf16x8*)(w2th + (size_t)ngf0*128 + kof);
      pwl0 = *(const bf16x8*)(w2tl + (size_t)ngf0*128 + kof);
      pwh1 = *(const bf16x8*)(w2th + (size_t)ngf1*128 + kof);
      pwl1 = *(const bf16x8*)(w2tl + (size_t)ngf1*128 + kof);
    }

    // ---- epilogue: 2 barriers (accumulate window, then flush+zero) ----
    __syncthreads();                 // plL zeroed & previous flush done
#pragma unroll
    for (int ft = 0; ft < 2; ++ft){
      f32x4 a = ft ? acc1 : acc0;
      int fl = ft*16 + row;           // local f in [0,32)
      int gf = fb*32 + fl;
      if (gf < 200){
        float bias = b2[gf];
        float s = 0.f;
        int gprev = -1;
#pragma unroll
        for (int r2 = 0; r2 < 4; ++r2){
          int g = nodebatch[r2];
          if (g >= 0){
            if (g != gprev){
              if (gprev >= 0){
                int dg = gprev - g0;
                if (dg < 8) atomicAdd(&plL[dg*32 + fl], s);
                else        atomicAdd(&pooled[(size_t)gprev*200 + gf], s);
              }
              gprev = g; s = 0.f;
            }
            s += silu_f(a[r2] + bias);
          }
        }
        if (gprev >= 0){
          int dg = gprev - g0;
          if (dg < 8) atomicAdd(&plL[dg*32 + fl], s);
          else        atomicAdd(&pooled[(size_t)gprev*200 + gf], s);
        }
      }
    }
    __syncthreads();
    // flush + zero in one pass; next fb's MFMAs overlap these atomics
    for (int idx = tid; idx < 256; idx += 128){
      float v = plL[idx];
      plL[idx] = 0.f;
      if (v != 0.f){
        int r2 = idx >> 5, f = idx & 31;
        int gf = fb*32 + f;
        if (gf < 200) atomicAdd(&pooled[(size_t)(g0+r2)*200 + gf], v);
      }
    }
  }
}

// ---------- head: mean finalize + MLP, one block per graph ----------
__global__ __launch_bounds__(256) void k_head(const float* __restrict__ pooled, const int* __restrict__ batch,
                       const float* __restrict__ W3, const float* __restrict__ b3,
                       const float* __restrict__ W4, const float* __restrict__ b4,
                       float* __restrict__ out, int N){
  __shared__ float pl[200];
  __shared__ float h3[100];
  int g = blockIdx.x; int tid = threadIdx.x;
  int lo=0, hi=N;
  while (lo<hi){ int m=(lo+hi)>>1; if (batch[m] < g) lo=m+1; else hi=m; }
  int s = lo;
  hi=N;
  while (lo<hi){ int m=(lo+hi)>>1; if (batch[m] < g+1) lo=m+1; else hi=m; }
  int e = lo;
  float inv = (e>s) ? 1.0f/(float)(e-s) : 0.0f;
  if (tid < 200) pl[tid] = pooled[(size_t)g*200 + tid] * inv;
  __syncthreads();
  if (tid < 100){
    float acc = b3[tid];
    for (int k=0;k<200;++k) acc += pl[k]*W3[k*100+tid];
    h3[tid] = silu_f(acc);
  }
  __syncthreads();
  if (tid < WF){
    float p = 0.f;
    if (tid < 100)      p  = h3[tid]     * W4[tid];
    if (tid + 64 < 100) p += h3[tid+64]  * W4[tid+64];
#pragma unroll
    for (int off=32; off; off>>=1) p += __shfl_down(p, off);
    if (tid==0) out[g] = p + b4[0];
  }
}

extern "C" void kernel_launch(void* const* d_in, const int* in_sizes, int n_in,
                              void* d_out, int out_size, void* d_ws, size_t ws_size,
                              hipStream_t stream){
  const float* x  = (const float*)d_in[0];
  const int*   ei = (const int*)  d_in[1];
  const int* batch= (const int*)  d_in[2];
  const float* W1 = (const float*)d_in[4];
  const float* b1 = (const float*)d_in[5];
  const float* W2 = (const float*)d_in[6];
  const float* b2 = (const float*)d_in[7];
  const float* W3 = (const float*)d_in[8];
  const float* b3 = (const float*)d_in[9];
  const float* W4 = (const float*)d_in[10];
  const float* b4 = (const float*)d_in[11];
  float* out = (float*)d_out;

  int N = in_sizes[0]/3;
  int E = in_sizes[1]/2;
  int G = out_size;
  const int* src = ei;
  const int* dst = ei + E;
  int NP = ((N + 63)/64)*64;   // padded rows for mm2 tile overrun

  char* base = (char*)d_ws; size_t off = 0;
  auto alloc = [&](size_t bytes)->void*{
    void* p = base + off;
    off = (off + bytes + 255) & ~(size_t)255;
    return p;
  };
  // zero-init via memset: cnt only (pooled zeroed in k_count_wconv)
  int*   cnt      = (int*)  alloc((size_t)N*4);
  size_t zbytes   = off;
  float* pooled   = (float*)alloc((size_t)G*200*4);
  int*   rowstart = (int*)  alloc((size_t)(N+1)*4);
  int*   cursor   = (int*)  alloc((size_t)N*4);
  int*   bsum     = (int*)  alloc(4096);
  int*   colsrc   = (int*)  alloc((size_t)E*4);
  float4* dxp     = (float4*)alloc((size_t)N*16);
  float4* z1      = (float4*)alloc((size_t)N*16);
  unsigned short* a2h = (unsigned short*)alloc((size_t)NP*128*2);
  unsigned short* a2l = (unsigned short*)alloc((size_t)NP*128*2);
  unsigned short* w2th = (unsigned short*)alloc((size_t)224*128*2);
  unsigned short* w2tl = (unsigned short*)alloc((size_t)224*128*2);
  (void)ws_size; (void)n_in;

  hipMemsetAsync(base, 0, zbytes, stream);
  int gE = (E+255)/256;
  int gW = (224*128+255)/256;
  int poolN = G*200;
  int gP = (poolN+255)/256;
  k_count_wconv<<<gE+gW+gP,256,0,stream>>>(dst, cnt, E, W2, w2th, w2tl, pooled, poolN, gE, gW);
  int nb = (N+2047)/2048;
  k_scan1<<<nb,256,0,stream>>>(cnt, rowstart, bsum, N);
  k_scan3<<<(N+255)/256,256,0,stream>>>(bsum, cnt, x, rowstart, cursor, dxp, N, E, nb);
  k_fill<<<gE,256,0,stream>>>(src, dst, cursor, colsrc, E);
  k_z1<<<(N+255)/256,256,0,stream>>>(dxp, rowstart, colsrc, z1, N);
  k_agg2f<<<(N+7)/8,256,0,stream>>>(z1, rowstart, colsrc, W1, b1, a2h, a2l, N);
  int nwg = (N+31)/32;
  dim3 gmm(nwg, 2);
  k_mm2<<<gmm,128,0,stream>>>(a2h, a2l, w2th, w2tl, b2, batch, pooled, N, nwg);
  k_head<<<G,256,0,stream>>>(pooled, batch, W3, b3, W4, b4, out, N);
}

// Round 26
// 167.187 us; speedup vs baseline: 1.0364x; 1.0003x over previous
//
#include <hip/hip_runtime.h>
#include <math.h>

#define WF 64

// hardware-native silu: v_exp_f32 (2^x) + v_rcp_f32 — ~5 VALU ops, ~1ulp
__device__ __forceinline__ float silu_f(float v){
  float e = __builtin_amdgcn_exp2f(v * -1.44269504088896340736f);
  return v * __builtin_amdgcn_rcpf(1.0f + e);
}

typedef __attribute__((ext_vector_type(8))) short bf16x8;
typedef __attribute__((ext_vector_type(4))) float f32x4;

__device__ __forceinline__ void bf16split(float v, unsigned short& h, unsigned short& l){
  unsigned int b = __float_as_uint(v);
  unsigned int hh = (b + 0x8000u) >> 16;
  float hf = __uint_as_float(hh << 16);
  float lo = v - hf;
  unsigned int bl = __float_as_uint(lo);
  h = (unsigned short)hh;
  l = (unsigned short)((bl + 0x8000u) >> 16);
}

// ---------- CSR count + W2 conversion + pooled zeroing (merged independent work) ----------
__global__ __launch_bounds__(256) void k_count_wconv(const int* __restrict__ dst, int* __restrict__ cnt, int E,
                       const float* __restrict__ W2,
                       unsigned short* __restrict__ w2th, unsigned short* __restrict__ w2tl,
                       float* __restrict__ pooled, int poolN,
                       int nCountBlocks, int nWBlocks){
  int b = blockIdx.x;
  if (b < nCountBlocks){
    int e = b*256 + threadIdx.x;
    if (e < E) atomicAdd(&cnt[dst[e]], 1);
  } else if (b < nCountBlocks + nWBlocks){
    int idx = (b - nCountBlocks)*256 + threadIdx.x;
    if (idx < 224*128){
      int f = idx >> 7, k = idx & 127;
      float v = (f < 200 && k < 100) ? W2[(size_t)k*200 + f] : 0.f;
      unsigned short h, l;
      bf16split(v, h, l);
      w2th[idx] = h;
      w2tl[idx] = l;
    }
  } else {
    // zero pooled (untouched until k_mm2, 4 launches later — no race)
    int idx = (b - nCountBlocks - nWBlocks)*256 + threadIdx.x;
    if (idx < poolN) pooled[idx] = 0.f;
  }
}

// block-local exclusive scan over chunks of 2048 (256 thr x 8 items)
__global__ __launch_bounds__(256) void k_scan1(const int* __restrict__ cnt, int* __restrict__ rowstart, int* __restrict__ bsum, int N){
  __shared__ int s[256];
  int tid = threadIdx.x;
  int base = blockIdx.x*2048 + tid*8;
  int loc[8]; int tsum = 0;
#pragma unroll
  for (int j=0;j<8;++j){ int idx=base+j; int v = (idx<N)?cnt[idx]:0; loc[j]=tsum; tsum+=v; }
  s[tid]=tsum; __syncthreads();
  for (int off=1; off<256; off<<=1){
    int v = (tid>=off)? s[tid-off] : 0;
    __syncthreads();
    s[tid] += v;
    __syncthreads();
  }
  int texc = s[tid] - tsum;
  if (tid==255) bsum[blockIdx.x] = s[255];
#pragma unroll
  for (int j=0;j<8;++j){ int idx=base+j; if (idx<N) rowstart[idx] = texc + loc[j]; }
}

// scan3: adds block prefix (from bsum), writes cursor and dxp = {di, di*x}
__global__ __launch_bounds__(256) void k_scan3(const int* __restrict__ bsum, const int* __restrict__ cnt,
                        const float* __restrict__ x,
                        int* __restrict__ rowstart, int* __restrict__ cursor,
                        float4* __restrict__ dxp,
                        int N, int E, int nb){
  __shared__ int boffs;
  int tid = threadIdx.x;
  int b = (blockIdx.x*blockDim.x) >> 11;   // uniform within block (256 <= 2048)
  if (tid < WF){
    int v = (tid < nb && tid < b) ? bsum[tid] : 0;
#pragma unroll
    for (int off=32; off; off>>=1) v += __shfl_down(v, off);
    if (tid==0) boffs = v;
  }
  __syncthreads();
  int idx = blockIdx.x*blockDim.x + tid;
  if (idx < N){
    int v = rowstart[idx] + boffs;
    rowstart[idx]=v; cursor[idx]=v;
    float di = rsqrtf((float)(cnt[idx]+1));   // +1 self-loop
    float4 o;
    o.x = di;
    o.y = di*x[3*idx+0];
    o.z = di*x[3*idx+1];
    o.w = di*x[3*idx+2];
    dxp[idx] = o;
  }
  if (idx==0) rowstart[N]=E;
}

// fill CSR: minimum scatter — one 4B colsrc write + cursor atomic per edge
__global__ __launch_bounds__(256) void k_fill(const int* __restrict__ src, const int* __restrict__ dst,
                       int* __restrict__ cursor, int* __restrict__ colsrc, int E){
  int e = blockIdx.x*blockDim.x + threadIdx.x;
  if (e < E){
    int d = dst[e];
    int pos = atomicAdd(&cursor[d], 1);
    colsrc[pos] = src[e];
  }
}

// ---------- z1: layer-1 aggregated input (3-dim CSR walk over dxp) ----------
__global__ __launch_bounds__(256) void k_z1(const float4* __restrict__ dxp,
                     const int* __restrict__ rowstart, const int* __restrict__ colsrc,
                     float4* __restrict__ z1, int N){
  int i = blockIdx.x*blockDim.x + threadIdx.x;
  if (i >= N) return;
  float4 self = dxp[i];
  float di = self.x;
  float sx = self.y, sy = self.z, sz = self.w;
  int jb = rowstart[i], je = rowstart[i+1];
  int j = jb;
  for (; j+3 < je; j += 4){
    float4 r0 = dxp[colsrc[j]];
    float4 r1 = dxp[colsrc[j+1]];
    float4 r2 = dxp[colsrc[j+2]];
    float4 r3 = dxp[colsrc[j+3]];
    sx += (r0.y + r1.y) + (r2.y + r3.y);
    sy += (r0.z + r1.z) + (r2.z + r3.z);
    sz += (r0.w + r1.w) + (r2.w + r3.w);
  }
  for (; j < je; ++j){
    float4 r = dxp[colsrc[j]];
    sx += r.y; sy += r.z; sz += r.w;
  }
  float4 o;
  o.x = di;
  o.y = di*sx; o.z = di*sy; o.w = di*sz;
  z1[i] = o;
}

// ---------- FUSED layer-1 transform + layer-2 aggregation -> bf16 planes ----------
// HALF-WAVE per node; 4x-unrolled neighbor loop for load ILP.
__global__ __launch_bounds__(256) void k_agg2f(const float4* __restrict__ z1,
                       const int* __restrict__ rowstart, const int* __restrict__ colsrc,
                       const float* __restrict__ W1, const float* __restrict__ b1,
                       unsigned short* __restrict__ a2h, unsigned short* __restrict__ a2l, int N){
  __shared__ float w[300];
  __shared__ float bb[100];
  int tid = threadIdx.x;
  for (int t=tid; t<300; t+=256) w[t]=W1[t];
  for (int t=tid; t<100; t+=256) bb[t]=b1[t];
  __syncthreads();

  int node = blockIdx.x*8 + (tid >> 5);
  int lane = tid & 31;
  if (node >= N) return;
  if (lane >= 25){
    int ko = 100 + (lane-25)*4;
    ushort4 z = make_ushort4(0,0,0,0);
    *(ushort4*)(a2h + (size_t)node*128 + ko) = z;
    *(ushort4*)(a2l + (size_t)node*128 + ko) = z;
    return;
  }
  int f0 = lane*4;
  float w0[4], w1[4], w2[4], b[4];
#pragma unroll
  for (int j=0;j<4;++j){
    w0[j] = w[f0+j]; w1[j] = w[100+f0+j]; w2[j] = w[200+f0+j]; b[j] = bb[f0+j];
  }

  float4 zn = z1[node];
  float din = zn.x;
  float acc[4];
#pragma unroll
  for (int j=0;j<4;++j){
    float h = silu_f(zn.y*w0[j] + zn.z*w1[j] + zn.w*w2[j] + b[j]);
    acc[j] = din*h;
  }
  int jb = rowstart[node], je = rowstart[node+1];
  int e = jb;
  for (; e+3 < je; e += 4){
    float4 zu0 = z1[colsrc[e]];
    float4 zu1 = z1[colsrc[e+1]];
    float4 zu2 = z1[colsrc[e+2]];
    float4 zu3 = z1[colsrc[e+3]];
#pragma unroll
    for (int j=0;j<4;++j){
      float h0 = silu_f(zu0.y*w0[j] + zu0.z*w1[j] + zu0.w*w2[j] + b[j]);
      float h1v = silu_f(zu1.y*w0[j] + zu1.z*w1[j] + zu1.w*w2[j] + b[j]);
      float h2v = silu_f(zu2.y*w0[j] + zu2.z*w1[j] + zu2.w*w2[j] + b[j]);
      float h3v = silu_f(zu3.y*w0[j] + zu3.z*w1[j] + zu3.w*w2[j] + b[j]);
      acc[j] += (zu0.x*h0 + zu1.x*h1v) + (zu2.x*h2v + zu3.x*h3v);
    }
  }
  for (; e < je; ++e){
    float4 zu = z1[colsrc[e]];
#pragma unroll
    for (int j=0;j<4;++j){
      float h = silu_f(zu.y*w0[j] + zu.z*w1[j] + zu.w*w2[j] + b[j]);
      acc[j] += zu.x*h;
    }
  }
  ushort4 h4, l4;
  bf16split(din*acc[0], h4.x, l4.x);
  bf16split(din*acc[1], h4.y, l4.y);
  bf16split(din*acc[2], h4.z, l4.z);
  bf16split(din*acc[3], h4.w, l4.w);
  *(ushort4*)(a2h + (size_t)node*128 + f0) = h4;
  *(ushort4*)(a2l + (size_t)node*128 + f0) = l4;
}

// ---------- layer 2 matmul via split-bf16 MFMA + fused mean-pool ----------
// R22 structure + FULL-FB W PRELOAD: all 16 W fragments of the fb are loaded
// into registers BEFORE any MFMA (independent loads -> 1 waitcnt instead of 4
// serial load->wait->mfma phases). VGPR ~124 < the ~144 hipcc grants 128-thr.
__global__ __launch_bounds__(128) void k_mm2(const unsigned short* __restrict__ a2h,
                      const unsigned short* __restrict__ a2l,
                      const unsigned short* __restrict__ w2th,
                      const unsigned short* __restrict__ w2tl,
                      const float* __restrict__ b2, const int* __restrict__ batch,
                      float* __restrict__ pooled, int N, int nwg){
  __shared__ float plL[256];
  int tid = threadIdx.x;
  int l = tid & 63, w = tid >> 6;   // w in {0,1}
  // bijective XCD swizzle on x
  int orig = blockIdx.x;
  int q = nwg >> 3, r = nwg & 7;
  int xcd = orig % 8, rk = orig / 8;
  int bid = (xcd < r) ? (xcd*(q+1) + rk) : (r*(q+1) + (xcd-r)*q + rk);
  int n0 = bid * 32;
  int row = l & 15;
  int kg  = l >> 4;
  int fb0 = blockIdx.y ? 4 : 0;
  int fb1 = blockIdx.y ? 7 : 4;

  const unsigned short* ah_p = a2h + (size_t)(n0 + w*16 + row)*128;
  const unsigned short* al_p = a2l + (size_t)(n0 + w*16 + row)*128;

  bf16x8 ahf[4], alf[4];
#pragma unroll
  for (int ks = 0; ks < 4; ++ks){
    int ko = ks*32 + kg*8;
    ahf[ks] = *(const bf16x8*)(ah_p + ko);
    alf[ks] = *(const bf16x8*)(al_p + ko);
  }

  // hoisted per-thread node->graph map (constant across fb loop)
  int g0 = batch[n0];
  int nodebatch[4];
#pragma unroll
  for (int r2 = 0; r2 < 4; ++r2){
    int node = n0 + w*16 + kg*4 + r2;
    nodebatch[r2] = (node < N) ? batch[node] : -1;
  }

  // zero plL once (first epilogue's entry barrier publishes it)
  for (int idx = tid; idx < 256; idx += 128) plL[idx] = 0.f;

  int kof = kg*8;
  // preload ALL 16 W fragments of the first fb
  bf16x8 wh0r[4], wl0r[4], wh1r[4], wl1r[4];
  {
    const unsigned short* wh0_p = w2th + (size_t)(fb0*32 + row)*128;
    const unsigned short* wl0_p = w2tl + (size_t)(fb0*32 + row)*128;
    const unsigned short* wh1_p = w2th + (size_t)(fb0*32 + 16 + row)*128;
    const unsigned short* wl1_p = w2tl + (size_t)(fb0*32 + 16 + row)*128;
#pragma unroll
    for (int ks = 0; ks < 4; ++ks){
      int ko = ks*32 + kof;
      wh0r[ks] = *(const bf16x8*)(wh0_p + ko);
      wl0r[ks] = *(const bf16x8*)(wl0_p + ko);
      wh1r[ks] = *(const bf16x8*)(wh1_p + ko);
      wl1r[ks] = *(const bf16x8*)(wl1_p + ko);
    }
  }

  for (int fb = fb0; fb < fb1; ++fb){
    f32x4 acc0 = {0.f,0.f,0.f,0.f};
    f32x4 acc1 = {0.f,0.f,0.f,0.f};
    // 24 back-to-back MFMAs from registers (single waitcnt before entry)
#pragma unroll
    for (int ks = 0; ks < 4; ++ks){
      acc0 = __builtin_amdgcn_mfma_f32_16x16x32_bf16(ahf[ks], wh0r[ks], acc0, 0, 0, 0);
      acc0 = __builtin_amdgcn_mfma_f32_16x16x32_bf16(ahf[ks], wl0r[ks], acc0, 0, 0, 0);
      acc0 = __builtin_amdgcn_mfma_f32_16x16x32_bf16(alf[ks], wh0r[ks], acc0, 0, 0, 0);
      acc1 = __builtin_amdgcn_mfma_f32_16x16x32_bf16(ahf[ks], wh1r[ks], acc1, 0, 0, 0);
      acc1 = __builtin_amdgcn_mfma_f32_16x16x32_bf16(ahf[ks], wl1r[ks], acc1, 0, 0, 0);
      acc1 = __builtin_amdgcn_mfma_f32_16x16x32_bf16(alf[ks], wh1r[ks], acc1, 0, 0, 0);
    }

    // preload next fb's 16 W fragments — latency hides under the epilogue
    if (fb+1 < fb1){
      const unsigned short* wh0_p = w2th + (size_t)((fb+1)*32 + row)*128;
      const unsigned short* wl0_p = w2tl + (size_t)((fb+1)*32 + row)*128;
      const unsigned short* wh1_p = w2th + (size_t)((fb+1)*32 + 16 + row)*128;
      const unsigned short* wl1_p = w2tl + (size_t)((fb+1)*32 + 16 + row)*128;
#pragma unroll
      for (int ks = 0; ks < 4; ++ks){
        int ko = ks*32 + kof;
        wh0r[ks] = *(const bf16x8*)(wh0_p + ko);
        wl0r[ks] = *(const bf16x8*)(wl0_p + ko);
        wh1r[ks] = *(const bf16x8*)(wh1_p + ko);
        wl1r[ks] = *(const bf16x8*)(wl1_p + ko);
      }
    }

    // ---- epilogue: 2 barriers (accumulate window, then flush+zero) ----
    __syncthreads();                 // plL zeroed & previous flush done
#pragma unroll
    for (int ft = 0; ft < 2; ++ft){
      f32x4 a = ft ? acc1 : acc0;
      int fl = ft*16 + row;           // local f in [0,32)
      int gf = fb*32 + fl;
      if (gf < 200){
        float bias = b2[gf];
        float s = 0.f;
        int gprev = -1;
#pragma unroll
        for (int r2 = 0; r2 < 4; ++r2){
          int g = nodebatch[r2];
          if (g >= 0){
            if (g != gprev){
              if (gprev >= 0){
                int dg = gprev - g0;
                if (dg < 8) atomicAdd(&plL[dg*32 + fl], s);
                else        atomicAdd(&pooled[(size_t)gprev*200 + gf], s);
              }
              gprev = g; s = 0.f;
            }
            s += silu_f(a[r2] + bias);
          }
        }
        if (gprev >= 0){
          int dg = gprev - g0;
          if (dg < 8) atomicAdd(&plL[dg*32 + fl], s);
          else        atomicAdd(&pooled[(size_t)gprev*200 + gf], s);
        }
      }
    }
    __syncthreads();
    // flush + zero in one pass; next fb's MFMAs overlap these atomics
    for (int idx = tid; idx < 256; idx += 128){
      float v = plL[idx];
      plL[idx] = 0.f;
      if (v != 0.f){
        int r2 = idx >> 5, f = idx & 31;
        int gf = fb*32 + f;
        if (gf < 200) atomicAdd(&pooled[(size_t)(g0+r2)*200 + gf], v);
      }
    }
  }
}

// ---------- head: mean finalize + MLP, one block per graph ----------
__global__ __launch_bounds__(256) void k_head(const float* __restrict__ pooled, const int* __restrict__ batch,
                       const float* __restrict__ W3, const float* __restrict__ b3,
                       const float* __restrict__ W4, const float* __restrict__ b4,
                       float* __restrict__ out, int N){
  __shared__ float pl[200];
  __shared__ float h3[100];
  int g = blockIdx.x; int tid = threadIdx.x;
  int lo=0, hi=N;
  while (lo<hi){ int m=(lo+hi)>>1; if (batch[m] < g) lo=m+1; else hi=m; }
  int s = lo;
  hi=N;
  while (lo<hi){ int m=(lo+hi)>>1; if (batch[m] < g+1) lo=m+1; else hi=m; }
  int e = lo;
  float inv = (e>s) ? 1.0f/(float)(e-s) : 0.0f;
  if (tid < 200) pl[tid] = pooled[(size_t)g*200 + tid] * inv;
  __syncthreads();
  if (tid < 100){
    float acc = b3[tid];
    for (int k=0;k<200;++k) acc += pl[k]*W3[k*100+tid];
    h3[tid] = silu_f(acc);
  }
  __syncthreads();
  if (tid < WF){
    float p = 0.f;
    if (tid < 100)      p  = h3[tid]     * W4[tid];
    if (tid + 64 < 100) p += h3[tid+64]  * W4[tid+64];
#pragma unroll
    for (int off=32; off; off>>=1) p += __shfl_down(p, off);
    if (tid==0) out[g] = p + b4[0];
  }
}

extern "C" void kernel_launch(void* const* d_in, const int* in_sizes, int n_in,
                              void* d_out, int out_size, void* d_ws, size_t ws_size,
                              hipStream_t stream){
  const float* x  = (const float*)d_in[0];
  const int*   ei = (const int*)  d_in[1];
  const int* batch= (const int*)  d_in[2];
  const float* W1 = (const float*)d_in[4];
  const float* b1 = (const float*)d_in[5];
  const float* W2 = (const float*)d_in[6];
  const float* b2 = (const float*)d_in[7];
  const float* W3 = (const float*)d_in[8];
  const float* b3 = (const float*)d_in[9];
  const float* W4 = (const float*)d_in[10];
  const float* b4 = (const float*)d_in[11];
  float* out = (float*)d_out;

  int N = in_sizes[0]/3;
  int E = in_sizes[1]/2;
  int G = out_size;
  const int* src = ei;
  const int* dst = ei + E;
  int NP = ((N + 63)/64)*64;   // padded rows for mm2 tile overrun

  char* base = (char*)d_ws; size_t off = 0;
  auto alloc = [&](size_t bytes)->void*{
    void* p = base + off;
    off = (off + bytes + 255) & ~(size_t)255;
    return p;
  };
  // zero-init via memset: cnt only (pooled zeroed in k_count_wconv)
  int*   cnt      = (int*)  alloc((size_t)N*4);
  size_t zbytes   = off;
  float* pooled   = (float*)alloc((size_t)G*200*4);
  int*   rowstart = (int*)  alloc((size_t)(N+1)*4);
  int*   cursor   = (int*)  alloc((size_t)N*4);
  int*   bsum     = (int*)  alloc(4096);
  int*   colsrc   = (int*)  alloc((size_t)E*4);
  float4* dxp     = (float4*)alloc((size_t)N*16);
  float4* z1      = (float4*)alloc((size_t)N*16);
  unsigned short* a2h = (unsigned short*)alloc((size_t)NP*128*2);
  unsigned short* a2l = (unsigned short*)alloc((size_t)NP*128*2);
  unsigned short* w2th = (unsigned short*)alloc((size_t)224*128*2);
  unsigned short* w2tl = (unsigned short*)alloc((size_t)224*128*2);
  (void)ws_size; (void)n_in;

  hipMemsetAsync(base, 0, zbytes, stream);
  int gE = (E+255)/256;
  int gW = (224*128+255)/256;
  int poolN = G*200;
  int gP = (poolN+255)/256;
  k_count_wconv<<<gE+gW+gP,256,0,stream>>>(dst, cnt, E, W2, w2th, w2tl, pooled, poolN, gE, gW);
  int nb = (N+2047)/2048;
  k_scan1<<<nb,256,0,stream>>>(cnt, rowstart, bsum, N);
  k_scan3<<<(N+255)/256,256,0,stream>>>(bsum, cnt, x, rowstart, cursor, dxp, N, E, nb);
  k_fill<<<gE,256,0,stream>>>(src, dst, cursor, colsrc, E);
  k_z1<<<(N+255)/256,256,0,stream>>>(dxp, rowstart, colsrc, z1, N);
  k_agg2f<<<(N+7)/8,256,0,stream>>>(z1, rowstart, colsrc, W1, b1, a2h, a2l, N);
  int nwg = (N+31)/32;
  dim3 gmm(nwg, 2);
  k_mm2<<<gmm,128,0,stream>>>(a2h, a2l, w2th, w2tl, b2, batch, pooled, N, nwg);
  k_head<<<G,256,0,stream>>>(pooled, batch, W3, b3, W4, b4, out, N);
}

// Round 27
// 166.703 us; speedup vs baseline: 1.0394x; 1.0029x over previous
//
#include <hip/hip_runtime.h>
#include <math.h>

#define WF 64

// hardware-native silu: v_exp_f32 (2^x) + v_rcp_f32 — ~5 VALU ops, ~1ulp
__device__ __forceinline__ float silu_f(float v){
  float e = __builtin_amdgcn_exp2f(v * -1.44269504088896340736f);
  return v * __builtin_amdgcn_rcpf(1.0f + e);
}

typedef __attribute__((ext_vector_type(8))) short bf16x8;
typedef __attribute__((ext_vector_type(4))) float f32x4;

__device__ __forceinline__ void bf16split(float v, unsigned short& h, unsigned short& l){
  unsigned int b = __float_as_uint(v);
  unsigned int hh = (b + 0x8000u) >> 16;
  float hf = __uint_as_float(hh << 16);
  float lo = v - hf;
  unsigned int bl = __float_as_uint(lo);
  h = (unsigned short)hh;
  l = (unsigned short)((bl + 0x8000u) >> 16);
}

// ---------- CSR count + W2 conversion + pooled zeroing (merged independent work) ----------
__global__ __launch_bounds__(256) void k_count_wconv(const int* __restrict__ dst, int* __restrict__ cnt, int E,
                       const float* __restrict__ W2,
                       unsigned short* __restrict__ w2th, unsigned short* __restrict__ w2tl,
                       float* __restrict__ pooled, int poolN,
                       int nCountBlocks, int nWBlocks){
  int b = blockIdx.x;
  if (b < nCountBlocks){
    int e = b*256 + threadIdx.x;
    if (e < E) atomicAdd(&cnt[dst[e]], 1);
  } else if (b < nCountBlocks + nWBlocks){
    int idx = (b - nCountBlocks)*256 + threadIdx.x;
    if (idx < 224*128){
      int f = idx >> 7, k = idx & 127;
      float v = (f < 200 && k < 100) ? W2[(size_t)k*200 + f] : 0.f;
      unsigned short h, l;
      bf16split(v, h, l);
      w2th[idx] = h;
      w2tl[idx] = l;
    }
  } else {
    // zero pooled (untouched until k_mm2, 4 launches later — no race)
    int idx = (b - nCountBlocks - nWBlocks)*256 + threadIdx.x;
    if (idx < poolN) pooled[idx] = 0.f;
  }
}

// block-local exclusive scan over chunks of 2048 (256 thr x 8 items)
__global__ __launch_bounds__(256) void k_scan1(const int* __restrict__ cnt, int* __restrict__ rowstart, int* __restrict__ bsum, int N){
  __shared__ int s[256];
  int tid = threadIdx.x;
  int base = blockIdx.x*2048 + tid*8;
  int loc[8]; int tsum = 0;
#pragma unroll
  for (int j=0;j<8;++j){ int idx=base+j; int v = (idx<N)?cnt[idx]:0; loc[j]=tsum; tsum+=v; }
  s[tid]=tsum; __syncthreads();
  for (int off=1; off<256; off<<=1){
    int v = (tid>=off)? s[tid-off] : 0;
    __syncthreads();
    s[tid] += v;
    __syncthreads();
  }
  int texc = s[tid] - tsum;
  if (tid==255) bsum[blockIdx.x] = s[255];
#pragma unroll
  for (int j=0;j<8;++j){ int idx=base+j; if (idx<N) rowstart[idx] = texc + loc[j]; }
}

// scan3: adds block prefix (from bsum), writes cursor and dxp = {di, di*x}
__global__ __launch_bounds__(256) void k_scan3(const int* __restrict__ bsum, const int* __restrict__ cnt,
                        const float* __restrict__ x,
                        int* __restrict__ rowstart, int* __restrict__ cursor,
                        float4* __restrict__ dxp,
                        int N, int E, int nb){
  __shared__ int boffs;
  int tid = threadIdx.x;
  int b = (blockIdx.x*blockDim.x) >> 11;   // uniform within block (256 <= 2048)
  if (tid < WF){
    int v = (tid < nb && tid < b) ? bsum[tid] : 0;
#pragma unroll
    for (int off=32; off; off>>=1) v += __shfl_down(v, off);
    if (tid==0) boffs = v;
  }
  __syncthreads();
  int idx = blockIdx.x*blockDim.x + tid;
  if (idx < N){
    int v = rowstart[idx] + boffs;
    rowstart[idx]=v; cursor[idx]=v;
    float di = rsqrtf((float)(cnt[idx]+1));   // +1 self-loop
    float4 o;
    o.x = di;
    o.y = di*x[3*idx+0];
    o.z = di*x[3*idx+1];
    o.w = di*x[3*idx+2];
    dxp[idx] = o;
  }
  if (idx==0) rowstart[N]=E;
}

// fill CSR: minimum scatter — one 4B colsrc write + cursor atomic per edge
__global__ __launch_bounds__(256) void k_fill(const int* __restrict__ src, const int* __restrict__ dst,
                       int* __restrict__ cursor, int* __restrict__ colsrc, int E){
  int e = blockIdx.x*blockDim.x + threadIdx.x;
  if (e < E){
    int d = dst[e];
    int pos = atomicAdd(&cursor[d], 1);
    colsrc[pos] = src[e];
  }
}

// ---------- z1: layer-1 aggregated input (3-dim CSR walk over dxp) ----------
__global__ __launch_bounds__(256) void k_z1(const float4* __restrict__ dxp,
                     const int* __restrict__ rowstart, const int* __restrict__ colsrc,
                     float4* __restrict__ z1, int N){
  int i = blockIdx.x*blockDim.x + threadIdx.x;
  if (i >= N) return;
  float4 self = dxp[i];
  float di = self.x;
  float sx = self.y, sy = self.z, sz = self.w;
  int jb = rowstart[i], je = rowstart[i+1];
  int j = jb;
  for (; j+3 < je; j += 4){
    float4 r0 = dxp[colsrc[j]];
    float4 r1 = dxp[colsrc[j+1]];
    float4 r2 = dxp[colsrc[j+2]];
    float4 r3 = dxp[colsrc[j+3]];
    sx += (r0.y + r1.y) + (r2.y + r3.y);
    sy += (r0.z + r1.z) + (r2.z + r3.z);
    sz += (r0.w + r1.w) + (r2.w + r3.w);
  }
  for (; j < je; ++j){
    float4 r = dxp[colsrc[j]];
    sx += r.y; sy += r.z; sz += r.w;
  }
  float4 o;
  o.x = di;
  o.y = di*sx; o.z = di*sy; o.w = di*sz;
  z1[i] = o;
}

// ---------- FUSED layer-1 transform + layer-2 aggregation -> bf16 planes ----------
// HALF-WAVE per node; 4x-unrolled neighbor loop for load ILP.
__global__ __launch_bounds__(256) void k_agg2f(const float4* __restrict__ z1,
                       const int* __restrict__ rowstart, const int* __restrict__ colsrc,
                       const float* __restrict__ W1, const float* __restrict__ b1,
                       unsigned short* __restrict__ a2h, unsigned short* __restrict__ a2l, int N){
  __shared__ float w[300];
  __shared__ float bb[100];
  int tid = threadIdx.x;
  for (int t=tid; t<300; t+=256) w[t]=W1[t];
  for (int t=tid; t<100; t+=256) bb[t]=b1[t];
  __syncthreads();

  int node = blockIdx.x*8 + (tid >> 5);
  int lane = tid & 31;
  if (node >= N) return;
  if (lane >= 25){
    int ko = 100 + (lane-25)*4;
    ushort4 z = make_ushort4(0,0,0,0);
    *(ushort4*)(a2h + (size_t)node*128 + ko) = z;
    *(ushort4*)(a2l + (size_t)node*128 + ko) = z;
    return;
  }
  int f0 = lane*4;
  float w0[4], w1[4], w2[4], b[4];
#pragma unroll
  for (int j=0;j<4;++j){
    w0[j] = w[f0+j]; w1[j] = w[100+f0+j]; w2[j] = w[200+f0+j]; b[j] = bb[f0+j];
  }

  float4 zn = z1[node];
  float din = zn.x;
  float acc[4];
#pragma unroll
  for (int j=0;j<4;++j){
    float h = silu_f(zn.y*w0[j] + zn.z*w1[j] + zn.w*w2[j] + b[j]);
    acc[j] = din*h;
  }
  int jb = rowstart[node], je = rowstart[node+1];
  int e = jb;
  for (; e+3 < je; e += 4){
    float4 zu0 = z1[colsrc[e]];
    float4 zu1 = z1[colsrc[e+1]];
    float4 zu2 = z1[colsrc[e+2]];
    float4 zu3 = z1[colsrc[e+3]];
#pragma unroll
    for (int j=0;j<4;++j){
      float h0 = silu_f(zu0.y*w0[j] + zu0.z*w1[j] + zu0.w*w2[j] + b[j]);
      float h1v = silu_f(zu1.y*w0[j] + zu1.z*w1[j] + zu1.w*w2[j] + b[j]);
      float h2v = silu_f(zu2.y*w0[j] + zu2.z*w1[j] + zu2.w*w2[j] + b[j]);
      float h3v = silu_f(zu3.y*w0[j] + zu3.z*w1[j] + zu3.w*w2[j] + b[j]);
      acc[j] += (zu0.x*h0 + zu1.x*h1v) + (zu2.x*h2v + zu3.x*h3v);
    }
  }
  for (; e < je; ++e){
    float4 zu = z1[colsrc[e]];
#pragma unroll
    for (int j=0;j<4;++j){
      float h = silu_f(zu.y*w0[j] + zu.z*w1[j] + zu.w*w2[j] + b[j]);
      acc[j] += zu.x*h;
    }
  }
  ushort4 h4, l4;
  bf16split(din*acc[0], h4.x, l4.x);
  bf16split(din*acc[1], h4.y, l4.y);
  bf16split(din*acc[2], h4.z, l4.z);
  bf16split(din*acc[3], h4.w, l4.w);
  *(ushort4*)(a2h + (size_t)node*128 + f0) = h4;
  *(ushort4*)(a2l + (size_t)node*128 + f0) = l4;
}

// ---------- layer 2 matmul via split-bf16 MFMA + fused mean-pool ----------
// Final config: 2-way fb split (blockIdx.y), A frags in regs, W fragment
// preload across fb (compiler re-materializes; neutral), 2-barrier epilogue.
__global__ __launch_bounds__(128) void k_mm2(const unsigned short* __restrict__ a2h,
                      const unsigned short* __restrict__ a2l,
                      const unsigned short* __restrict__ w2th,
                      const unsigned short* __restrict__ w2tl,
                      const float* __restrict__ b2, const int* __restrict__ batch,
                      float* __restrict__ pooled, int N, int nwg){
  __shared__ float plL[256];
  int tid = threadIdx.x;
  int l = tid & 63, w = tid >> 6;   // w in {0,1}
  // bijective XCD swizzle on x
  int orig = blockIdx.x;
  int q = nwg >> 3, r = nwg & 7;
  int xcd = orig % 8, rk = orig / 8;
  int bid = (xcd < r) ? (xcd*(q+1) + rk) : (r*(q+1) + (xcd-r)*q + rk);
  int n0 = bid * 32;
  int row = l & 15;
  int kg  = l >> 4;
  int fb0 = blockIdx.y ? 4 : 0;
  int fb1 = blockIdx.y ? 7 : 4;

  const unsigned short* ah_p = a2h + (size_t)(n0 + w*16 + row)*128;
  const unsigned short* al_p = a2l + (size_t)(n0 + w*16 + row)*128;

  bf16x8 ahf[4], alf[4];
#pragma unroll
  for (int ks = 0; ks < 4; ++ks){
    int ko = ks*32 + kg*8;
    ahf[ks] = *(const bf16x8*)(ah_p + ko);
    alf[ks] = *(const bf16x8*)(al_p + ko);
  }

  // hoisted per-thread node->graph map (constant across fb loop)
  int g0 = batch[n0];
  int nodebatch[4];
#pragma unroll
  for (int r2 = 0; r2 < 4; ++r2){
    int node = n0 + w*16 + kg*4 + r2;
    nodebatch[r2] = (node < N) ? batch[node] : -1;
  }

  // zero plL once (first epilogue's entry barrier publishes it)
  for (int idx = tid; idx < 256; idx += 128) plL[idx] = 0.f;

  int kof = kg*8;
  // preload ALL 16 W fragments of the first fb
  bf16x8 wh0r[4], wl0r[4], wh1r[4], wl1r[4];
  {
    const unsigned short* wh0_p = w2th + (size_t)(fb0*32 + row)*128;
    const unsigned short* wl0_p = w2tl + (size_t)(fb0*32 + row)*128;
    const unsigned short* wh1_p = w2th + (size_t)(fb0*32 + 16 + row)*128;
    const unsigned short* wl1_p = w2tl + (size_t)(fb0*32 + 16 + row)*128;
#pragma unroll
    for (int ks = 0; ks < 4; ++ks){
      int ko = ks*32 + kof;
      wh0r[ks] = *(const bf16x8*)(wh0_p + ko);
      wl0r[ks] = *(const bf16x8*)(wl0_p + ko);
      wh1r[ks] = *(const bf16x8*)(wh1_p + ko);
      wl1r[ks] = *(const bf16x8*)(wl1_p + ko);
    }
  }

  for (int fb = fb0; fb < fb1; ++fb){
    f32x4 acc0 = {0.f,0.f,0.f,0.f};
    f32x4 acc1 = {0.f,0.f,0.f,0.f};
#pragma unroll
    for (int ks = 0; ks < 4; ++ks){
      acc0 = __builtin_amdgcn_mfma_f32_16x16x32_bf16(ahf[ks], wh0r[ks], acc0, 0, 0, 0);
      acc0 = __builtin_amdgcn_mfma_f32_16x16x32_bf16(ahf[ks], wl0r[ks], acc0, 0, 0, 0);
      acc0 = __builtin_amdgcn_mfma_f32_16x16x32_bf16(alf[ks], wh0r[ks], acc0, 0, 0, 0);
      acc1 = __builtin_amdgcn_mfma_f32_16x16x32_bf16(ahf[ks], wh1r[ks], acc1, 0, 0, 0);
      acc1 = __builtin_amdgcn_mfma_f32_16x16x32_bf16(ahf[ks], wl1r[ks], acc1, 0, 0, 0);
      acc1 = __builtin_amdgcn_mfma_f32_16x16x32_bf16(alf[ks], wh1r[ks], acc1, 0, 0, 0);
    }

    // preload next fb's 16 W fragments — latency hides under the epilogue
    if (fb+1 < fb1){
      const unsigned short* wh0_p = w2th + (size_t)((fb+1)*32 + row)*128;
      const unsigned short* wl0_p = w2tl + (size_t)((fb+1)*32 + row)*128;
      const unsigned short* wh1_p = w2th + (size_t)((fb+1)*32 + 16 + row)*128;
      const unsigned short* wl1_p = w2tl + (size_t)((fb+1)*32 + 16 + row)*128;
#pragma unroll
      for (int ks = 0; ks < 4; ++ks){
        int ko = ks*32 + kof;
        wh0r[ks] = *(const bf16x8*)(wh0_p + ko);
        wl0r[ks] = *(const bf16x8*)(wl0_p + ko);
        wh1r[ks] = *(const bf16x8*)(wh1_p + ko);
        wl1r[ks] = *(const bf16x8*)(wl1_p + ko);
      }
    }

    // ---- epilogue: 2 barriers (accumulate window, then flush+zero) ----
    __syncthreads();                 // plL zeroed & previous flush done
#pragma unroll
    for (int ft = 0; ft < 2; ++ft){
      f32x4 a = ft ? acc1 : acc0;
      int fl = ft*16 + row;           // local f in [0,32)
      int gf = fb*32 + fl;
      if (gf < 200){
        float bias = b2[gf];
        float s = 0.f;
        int gprev = -1;
#pragma unroll
        for (int r2 = 0; r2 < 4; ++r2){
          int g = nodebatch[r2];
          if (g >= 0){
            if (g != gprev){
              if (gprev >= 0){
                int dg = gprev - g0;
                if (dg < 8) atomicAdd(&plL[dg*32 + fl], s);
                else        atomicAdd(&pooled[(size_t)gprev*200 + gf], s);
              }
              gprev = g; s = 0.f;
            }
            s += silu_f(a[r2] + bias);
          }
        }
        if (gprev >= 0){
          int dg = gprev - g0;
          if (dg < 8) atomicAdd(&plL[dg*32 + fl], s);
          else        atomicAdd(&pooled[(size_t)gprev*200 + gf], s);
        }
      }
    }
    __syncthreads();
    // flush + zero in one pass; next fb's MFMAs overlap these atomics
    for (int idx = tid; idx < 256; idx += 128){
      float v = plL[idx];
      plL[idx] = 0.f;
      if (v != 0.f){
        int r2 = idx >> 5, f = idx & 31;
        int gf = fb*32 + f;
        if (gf < 200) atomicAdd(&pooled[(size_t)(g0+r2)*200 + gf], v);
      }
    }
  }
}

// ---------- head: mean finalize + MLP, one block per graph ----------
__global__ __launch_bounds__(256) void k_head(const float* __restrict__ pooled, const int* __restrict__ batch,
                       const float* __restrict__ W3, const float* __restrict__ b3,
                       const float* __restrict__ W4, const float* __restrict__ b4,
                       float* __restrict__ out, int N){
  __shared__ float pl[200];
  __shared__ float h3[100];
  int g = blockIdx.x; int tid = threadIdx.x;
  int lo=0, hi=N;
  while (lo<hi){ int m=(lo+hi)>>1; if (batch[m] < g) lo=m+1; else hi=m; }
  int s = lo;
  hi=N;
  while (lo<hi){ int m=(lo+hi)>>1; if (batch[m] < g+1) lo=m+1; else hi=m; }
  int e = lo;
  float inv = (e>s) ? 1.0f/(float)(e-s) : 0.0f;
  if (tid < 200) pl[tid] = pooled[(size_t)g*200 + tid] * inv;
  __syncthreads();
  if (tid < 100){
    float acc = b3[tid];
    for (int k=0;k<200;++k) acc += pl[k]*W3[k*100+tid];
    h3[tid] = silu_f(acc);
  }
  __syncthreads();
  if (tid < WF){
    float p = 0.f;
    if (tid < 100)      p  = h3[tid]     * W4[tid];
    if (tid + 64 < 100) p += h3[tid+64]  * W4[tid+64];
#pragma unroll
    for (int off=32; off; off>>=1) p += __shfl_down(p, off);
    if (tid==0) out[g] = p + b4[0];
  }
}

extern "C" void kernel_launch(void* const* d_in, const int* in_sizes, int n_in,
                              void* d_out, int out_size, void* d_ws, size_t ws_size,
                              hipStream_t stream){
  const float* x  = (const float*)d_in[0];
  const int*   ei = (const int*)  d_in[1];
  const int* batch= (const int*)  d_in[2];
  const float* W1 = (const float*)d_in[4];
  const float* b1 = (const float*)d_in[5];
  const float* W2 = (const float*)d_in[6];
  const float* b2 = (const float*)d_in[7];
  const float* W3 = (const float*)d_in[8];
  const float* b3 = (const float*)d_in[9];
  const float* W4 = (const float*)d_in[10];
  const float* b4 = (const float*)d_in[11];
  float* out = (float*)d_out;

  int N = in_sizes[0]/3;
  int E = in_sizes[1]/2;
  int G = out_size;
  const int* src = ei;
  const int* dst = ei + E;
  int NP = ((N + 63)/64)*64;   // padded rows for mm2 tile overrun

  char* base = (char*)d_ws; size_t off = 0;
  auto alloc = [&](size_t bytes)->void*{
    void* p = base + off;
    off = (off + bytes + 255) & ~(size_t)255;
    return p;
  };
  // zero-init via memset: cnt only (pooled zeroed in k_count_wconv)
  int*   cnt      = (int*)  alloc((size_t)N*4);
  size_t zbytes   = off;
  float* pooled   = (float*)alloc((size_t)G*200*4);
  int*   rowstart = (int*)  alloc((size_t)(N+1)*4);
  int*   cursor   = (int*)  alloc((size_t)N*4);
  int*   bsum     = (int*)  alloc(4096);
  int*   colsrc   = (int*)  alloc((size_t)E*4);
  float4* dxp     = (float4*)alloc((size_t)N*16);
  float4* z1      = (float4*)alloc((size_t)N*16);
  unsigned short* a2h = (unsigned short*)alloc((size_t)NP*128*2);
  unsigned short* a2l = (unsigned short*)alloc((size_t)NP*128*2);
  unsigned short* w2th = (unsigned short*)alloc((size_t)224*128*2);
  unsigned short* w2tl = (unsigned short*)alloc((size_t)224*128*2);
  (void)ws_size; (void)n_in;

  hipMemsetAsync(base, 0, zbytes, stream);
  int gE = (E+255)/256;
  int gW = (224*128+255)/256;
  int poolN = G*200;
  int gP = (poolN+255)/256;
  k_count_wconv<<<gE+gW+gP,256,0,stream>>>(dst, cnt, E, W2, w2th, w2tl, pooled, poolN, gE, gW);
  int nb = (N+2047)/2048;
  k_scan1<<<nb,256,0,stream>>>(cnt, rowstart, bsum, N);
  k_scan3<<<(N+255)/256,256,0,stream>>>(bsum, cnt, x, rowstart, cursor, dxp, N, E, nb);
  k_fill<<<gE,256,0,stream>>>(src, dst, cursor, colsrc, E);
  k_z1<<<(N+255)/256,256,0,stream>>>(dxp, rowstart, colsrc, z1, N);
  k_agg2f<<<(N+7)/8,256,0,stream>>>(z1, rowstart, colsrc, W1, b1, a2h, a2l, N);
  int nwg = (N+31)/32;
  dim3 gmm(nwg, 2);
  k_mm2<<<gmm,128,0,stream>>>(a2h, a2l, w2th, w2tl, b2, batch, pooled, N, nwg);
  k_head<<<G,256,0,stream>>>(pooled, batch, W3, b3, W4, b4, out, N);
}

// Round 28
// 166.660 us; speedup vs baseline: 1.0397x; 1.0003x over previous
//
#include <hip/hip_runtime.h>
#include <math.h>

#define WF 64

// hardware-native silu: v_exp_f32 (2^x) + v_rcp_f32 — ~5 VALU ops, ~1ulp
__device__ __forceinline__ float silu_f(float v){
  float e = __builtin_amdgcn_exp2f(v * -1.44269504088896340736f);
  return v * __builtin_amdgcn_rcpf(1.0f + e);
}

typedef __attribute__((ext_vector_type(8))) short bf16x8;
typedef __attribute__((ext_vector_type(4))) float f32x4;

__device__ __forceinline__ void bf16split(float v, unsigned short& h, unsigned short& l){
  unsigned int b = __float_as_uint(v);
  unsigned int hh = (b + 0x8000u) >> 16;
  float hf = __uint_as_float(hh << 16);
  float lo = v - hf;
  unsigned int bl = __float_as_uint(lo);
  h = (unsigned short)hh;
  l = (unsigned short)((bl + 0x8000u) >> 16);
}

// ---------- CSR count + W2 conversion + pooled zeroing (merged independent work) ----------
__global__ __launch_bounds__(256) void k_count_wconv(const int* __restrict__ dst, int* __restrict__ cnt, int E,
                       const float* __restrict__ W2,
                       unsigned short* __restrict__ w2th, unsigned short* __restrict__ w2tl,
                       float* __restrict__ pooled, int poolN,
                       int nCountBlocks, int nWBlocks){
  int b = blockIdx.x;
  if (b < nCountBlocks){
    int e = b*256 + threadIdx.x;
    if (e < E) atomicAdd(&cnt[dst[e]], 1);
  } else if (b < nCountBlocks + nWBlocks){
    int idx = (b - nCountBlocks)*256 + threadIdx.x;
    if (idx < 224*128){
      int f = idx >> 7, k = idx & 127;
      float v = (f < 200 && k < 100) ? W2[(size_t)k*200 + f] : 0.f;
      unsigned short h, l;
      bf16split(v, h, l);
      w2th[idx] = h;
      w2tl[idx] = l;
    }
  } else {
    // zero pooled (untouched until k_mm2, 4 launches later — no race)
    int idx = (b - nCountBlocks - nWBlocks)*256 + threadIdx.x;
    if (idx < poolN) pooled[idx] = 0.f;
  }
}

// block-local exclusive scan over chunks of 2048 (256 thr x 8 items)
__global__ __launch_bounds__(256) void k_scan1(const int* __restrict__ cnt, int* __restrict__ rowstart, int* __restrict__ bsum, int N){
  __shared__ int s[256];
  int tid = threadIdx.x;
  int base = blockIdx.x*2048 + tid*8;
  int loc[8]; int tsum = 0;
#pragma unroll
  for (int j=0;j<8;++j){ int idx=base+j; int v = (idx<N)?cnt[idx]:0; loc[j]=tsum; tsum+=v; }
  s[tid]=tsum; __syncthreads();
  for (int off=1; off<256; off<<=1){
    int v = (tid>=off)? s[tid-off] : 0;
    __syncthreads();
    s[tid] += v;
    __syncthreads();
  }
  int texc = s[tid] - tsum;
  if (tid==255) bsum[blockIdx.x] = s[255];
#pragma unroll
  for (int j=0;j<8;++j){ int idx=base+j; if (idx<N) rowstart[idx] = texc + loc[j]; }
}

// scan3: adds block prefix (from bsum), writes cursor and dxp = {di, di*x}
__global__ __launch_bounds__(256) void k_scan3(const int* __restrict__ bsum, const int* __restrict__ cnt,
                        const float* __restrict__ x,
                        int* __restrict__ rowstart, int* __restrict__ cursor,
                        float4* __restrict__ dxp,
                        int N, int E, int nb){
  __shared__ int boffs;
  int tid = threadIdx.x;
  int b = (blockIdx.x*blockDim.x) >> 11;   // uniform within block (256 <= 2048)
  if (tid < WF){
    int v = (tid < nb && tid < b) ? bsum[tid] : 0;
#pragma unroll
    for (int off=32; off; off>>=1) v += __shfl_down(v, off);
    if (tid==0) boffs = v;
  }
  __syncthreads();
  int idx = blockIdx.x*blockDim.x + tid;
  if (idx < N){
    int v = rowstart[idx] + boffs;
    rowstart[idx]=v; cursor[idx]=v;
    float di = rsqrtf((float)(cnt[idx]+1));   // +1 self-loop
    float4 o;
    o.x = di;
    o.y = di*x[3*idx+0];
    o.z = di*x[3*idx+1];
    o.w = di*x[3*idx+2];
    dxp[idx] = o;
  }
  if (idx==0) rowstart[N]=E;
}

// fill CSR: minimum scatter — one 4B colsrc write + cursor atomic per edge
__global__ __launch_bounds__(256) void k_fill(const int* __restrict__ src, const int* __restrict__ dst,
                       int* __restrict__ cursor, int* __restrict__ colsrc, int E){
  int e = blockIdx.x*blockDim.x + threadIdx.x;
  if (e < E){
    int d = dst[e];
    int pos = atomicAdd(&cursor[d], 1);
    colsrc[pos] = src[e];
  }
}

// ---------- z1: layer-1 aggregated input (3-dim CSR walk over dxp) ----------
__global__ __launch_bounds__(256) void k_z1(const float4* __restrict__ dxp,
                     const int* __restrict__ rowstart, const int* __restrict__ colsrc,
                     float4* __restrict__ z1, int N){
  int i = blockIdx.x*blockDim.x + threadIdx.x;
  if (i >= N) return;
  float4 self = dxp[i];
  float di = self.x;
  float sx = self.y, sy = self.z, sz = self.w;
  int jb = rowstart[i], je = rowstart[i+1];
  int j = jb;
  for (; j+3 < je; j += 4){
    float4 r0 = dxp[colsrc[j]];
    float4 r1 = dxp[colsrc[j+1]];
    float4 r2 = dxp[colsrc[j+2]];
    float4 r3 = dxp[colsrc[j+3]];
    sx += (r0.y + r1.y) + (r2.y + r3.y);
    sy += (r0.z + r1.z) + (r2.z + r3.z);
    sz += (r0.w + r1.w) + (r2.w + r3.w);
  }
  for (; j < je; ++j){
    float4 r = dxp[colsrc[j]];
    sx += r.y; sy += r.z; sz += r.w;
  }
  float4 o;
  o.x = di;
  o.y = di*sx; o.z = di*sy; o.w = di*sz;
  z1[i] = o;
}

// ---------- FUSED layer-1 transform + layer-2 aggregation -> bf16 planes ----------
// HALF-WAVE per node; 4x-unrolled neighbor loop for load ILP.
__global__ __launch_bounds__(256) void k_agg2f(const float4* __restrict__ z1,
                       const int* __restrict__ rowstart, const int* __restrict__ colsrc,
                       const float* __restrict__ W1, const float* __restrict__ b1,
                       unsigned short* __restrict__ a2h, unsigned short* __restrict__ a2l, int N){
  __shared__ float w[300];
  __shared__ float bb[100];
  int tid = threadIdx.x;
  for (int t=tid; t<300; t+=256) w[t]=W1[t];
  for (int t=tid; t<100; t+=256) bb[t]=b1[t];
  __syncthreads();

  int node = blockIdx.x*8 + (tid >> 5);
  int lane = tid & 31;
  if (node >= N) return;
  if (lane >= 25){
    int ko = 100 + (lane-25)*4;
    ushort4 z = make_ushort4(0,0,0,0);
    *(ushort4*)(a2h + (size_t)node*128 + ko) = z;
    *(ushort4*)(a2l + (size_t)node*128 + ko) = z;
    return;
  }
  int f0 = lane*4;
  float w0[4], w1[4], w2[4], b[4];
#pragma unroll
  for (int j=0;j<4;++j){
    w0[j] = w[f0+j]; w1[j] = w[100+f0+j]; w2[j] = w[200+f0+j]; b[j] = bb[f0+j];
  }

  float4 zn = z1[node];
  float din = zn.x;
  float acc[4];
#pragma unroll
  for (int j=0;j<4;++j){
    float h = silu_f(zn.y*w0[j] + zn.z*w1[j] + zn.w*w2[j] + b[j]);
    acc[j] = din*h;
  }
  int jb = rowstart[node], je = rowstart[node+1];
  int e = jb;
  for (; e+3 < je; e += 4){
    float4 zu0 = z1[colsrc[e]];
    float4 zu1 = z1[colsrc[e+1]];
    float4 zu2 = z1[colsrc[e+2]];
    float4 zu3 = z1[colsrc[e+3]];
#pragma unroll
    for (int j=0;j<4;++j){
      float h0 = silu_f(zu0.y*w0[j] + zu0.z*w1[j] + zu0.w*w2[j] + b[j]);
      float h1v = silu_f(zu1.y*w0[j] + zu1.z*w1[j] + zu1.w*w2[j] + b[j]);
      float h2v = silu_f(zu2.y*w0[j] + zu2.z*w1[j] + zu2.w*w2[j] + b[j]);
      float h3v = silu_f(zu3.y*w0[j] + zu3.z*w1[j] + zu3.w*w2[j] + b[j]);
      acc[j] += (zu0.x*h0 + zu1.x*h1v) + (zu2.x*h2v + zu3.x*h3v);
    }
  }
  for (; e < je; ++e){
    float4 zu = z1[colsrc[e]];
#pragma unroll
    for (int j=0;j<4;++j){
      float h = silu_f(zu.y*w0[j] + zu.z*w1[j] + zu.w*w2[j] + b[j]);
      acc[j] += zu.x*h;
    }
  }
  ushort4 h4, l4;
  bf16split(din*acc[0], h4.x, l4.x);
  bf16split(din*acc[1], h4.y, l4.y);
  bf16split(din*acc[2], h4.z, l4.z);
  bf16split(din*acc[3], h4.w, l4.w);
  *(ushort4*)(a2h + (size_t)node*128 + f0) = h4;
  *(ushort4*)(a2l + (size_t)node*128 + f0) = l4;
}

// ---------- layer 2 matmul via split-bf16 MFMA + fused mean-pool ----------
// Final config: 2-way fb split (blockIdx.y), A frags in regs, W fragment
// preload across fb (compiler re-materializes; neutral), 2-barrier epilogue.
__global__ __launch_bounds__(128) void k_mm2(const unsigned short* __restrict__ a2h,
                      const unsigned short* __restrict__ a2l,
                      const unsigned short* __restrict__ w2th,
                      const unsigned short* __restrict__ w2tl,
                      const float* __restrict__ b2, const int* __restrict__ batch,
                      float* __restrict__ pooled, int N, int nwg){
  __shared__ float plL[256];
  int tid = threadIdx.x;
  int l = tid & 63, w = tid >> 6;   // w in {0,1}
  // bijective XCD swizzle on x
  int orig = blockIdx.x;
  int q = nwg >> 3, r = nwg & 7;
  int xcd = orig % 8, rk = orig / 8;
  int bid = (xcd < r) ? (xcd*(q+1) + rk) : (r*(q+1) + (xcd-r)*q + rk);
  int n0 = bid * 32;
  int row = l & 15;
  int kg  = l >> 4;
  int fb0 = blockIdx.y ? 4 : 0;
  int fb1 = blockIdx.y ? 7 : 4;

  const unsigned short* ah_p = a2h + (size_t)(n0 + w*16 + row)*128;
  const unsigned short* al_p = a2l + (size_t)(n0 + w*16 + row)*128;

  bf16x8 ahf[4], alf[4];
#pragma unroll
  for (int ks = 0; ks < 4; ++ks){
    int ko = ks*32 + kg*8;
    ahf[ks] = *(const bf16x8*)(ah_p + ko);
    alf[ks] = *(const bf16x8*)(al_p + ko);
  }

  // hoisted per-thread node->graph map (constant across fb loop)
  int g0 = batch[n0];
  int nodebatch[4];
#pragma unroll
  for (int r2 = 0; r2 < 4; ++r2){
    int node = n0 + w*16 + kg*4 + r2;
    nodebatch[r2] = (node < N) ? batch[node] : -1;
  }

  // zero plL once (first epilogue's entry barrier publishes it)
  for (int idx = tid; idx < 256; idx += 128) plL[idx] = 0.f;

  int kof = kg*8;
  // preload ALL 16 W fragments of the first fb
  bf16x8 wh0r[4], wl0r[4], wh1r[4], wl1r[4];
  {
    const unsigned short* wh0_p = w2th + (size_t)(fb0*32 + row)*128;
    const unsigned short* wl0_p = w2tl + (size_t)(fb0*32 + row)*128;
    const unsigned short* wh1_p = w2th + (size_t)(fb0*32 + 16 + row)*128;
    const unsigned short* wl1_p = w2tl + (size_t)(fb0*32 + 16 + row)*128;
#pragma unroll
    for (int ks = 0; ks < 4; ++ks){
      int ko = ks*32 + kof;
      wh0r[ks] = *(const bf16x8*)(wh0_p + ko);
      wl0r[ks] = *(const bf16x8*)(wl0_p + ko);
      wh1r[ks] = *(const bf16x8*)(wh1_p + ko);
      wl1r[ks] = *(const bf16x8*)(wl1_p + ko);
    }
  }

  for (int fb = fb0; fb < fb1; ++fb){
    f32x4 acc0 = {0.f,0.f,0.f,0.f};
    f32x4 acc1 = {0.f,0.f,0.f,0.f};
#pragma unroll
    for (int ks = 0; ks < 4; ++ks){
      acc0 = __builtin_amdgcn_mfma_f32_16x16x32_bf16(ahf[ks], wh0r[ks], acc0, 0, 0, 0);
      acc0 = __builtin_amdgcn_mfma_f32_16x16x32_bf16(ahf[ks], wl0r[ks], acc0, 0, 0, 0);
      acc0 = __builtin_amdgcn_mfma_f32_16x16x32_bf16(alf[ks], wh0r[ks], acc0, 0, 0, 0);
      acc1 = __builtin_amdgcn_mfma_f32_16x16x32_bf16(ahf[ks], wh1r[ks], acc1, 0, 0, 0);
      acc1 = __builtin_amdgcn_mfma_f32_16x16x32_bf16(ahf[ks], wl1r[ks], acc1, 0, 0, 0);
      acc1 = __builtin_amdgcn_mfma_f32_16x16x32_bf16(alf[ks], wh1r[ks], acc1, 0, 0, 0);
    }

    // preload next fb's 16 W fragments — latency hides under the epilogue
    if (fb+1 < fb1){
      const unsigned short* wh0_p = w2th + (size_t)((fb+1)*32 + row)*128;
      const unsigned short* wl0_p = w2tl + (size_t)((fb+1)*32 + row)*128;
      const unsigned short* wh1_p = w2th + (size_t)((fb+1)*32 + 16 + row)*128;
      const unsigned short* wl1_p = w2tl + (size_t)((fb+1)*32 + 16 + row)*128;
#pragma unroll
      for (int ks = 0; ks < 4; ++ks){
        int ko = ks*32 + kof;
        wh0r[ks] = *(const bf16x8*)(wh0_p + ko);
        wl0r[ks] = *(const bf16x8*)(wl0_p + ko);
        wh1r[ks] = *(const bf16x8*)(wh1_p + ko);
        wl1r[ks] = *(const bf16x8*)(wl1_p + ko);
      }
    }

    // ---- epilogue: 2 barriers (accumulate window, then flush+zero) ----
    __syncthreads();                 // plL zeroed & previous flush done
#pragma unroll
    for (int ft = 0; ft < 2; ++ft){
      f32x4 a = ft ? acc1 : acc0;
      int fl = ft*16 + row;           // local f in [0,32)
      int gf = fb*32 + fl;
      if (gf < 200){
        float bias = b2[gf];
        float s = 0.f;
        int gprev = -1;
#pragma unroll
        for (int r2 = 0; r2 < 4; ++r2){
          int g = nodebatch[r2];
          if (g >= 0){
            if (g != gprev){
              if (gprev >= 0){
                int dg = gprev - g0;
                if (dg < 8) atomicAdd(&plL[dg*32 + fl], s);
                else        atomicAdd(&pooled[(size_t)gprev*200 + gf], s);
              }
              gprev = g; s = 0.f;
            }
            s += silu_f(a[r2] + bias);
          }
        }
        if (gprev >= 0){
          int dg = gprev - g0;
          if (dg < 8) atomicAdd(&plL[dg*32 + fl], s);
          else        atomicAdd(&pooled[(size_t)gprev*200 + gf], s);
        }
      }
    }
    __syncthreads();
    // flush + zero in one pass; next fb's MFMAs overlap these atomics
    for (int idx = tid; idx < 256; idx += 128){
      float v = plL[idx];
      plL[idx] = 0.f;
      if (v != 0.f){
        int r2 = idx >> 5, f = idx & 31;
        int gf = fb*32 + f;
        if (gf < 200) atomicAdd(&pooled[(size_t)(g0+r2)*200 + gf], v);
      }
    }
  }
}

// ---------- head: mean finalize + MLP, one block per graph ----------
__global__ __launch_bounds__(256) void k_head(const float* __restrict__ pooled, const int* __restrict__ batch,
                       const float* __restrict__ W3, const float* __restrict__ b3,
                       const float* __restrict__ W4, const float* __restrict__ b4,
                       float* __restrict__ out, int N){
  __shared__ float pl[200];
  __shared__ float h3[100];
  int g = blockIdx.x; int tid = threadIdx.x;
  int lo=0, hi=N;
  while (lo<hi){ int m=(lo+hi)>>1; if (batch[m] < g) lo=m+1; else hi=m; }
  int s = lo;
  hi=N;
  while (lo<hi){ int m=(lo+hi)>>1; if (batch[m] < g+1) lo=m+1; else hi=m; }
  int e = lo;
  float inv = (e>s) ? 1.0f/(float)(e-s) : 0.0f;
  if (tid < 200) pl[tid] = pooled[(size_t)g*200 + tid] * inv;
  __syncthreads();
  if (tid < 100){
    float acc = b3[tid];
    for (int k=0;k<200;++k) acc += pl[k]*W3[k*100+tid];
    h3[tid] = silu_f(acc);
  }
  __syncthreads();
  if (tid < WF){
    float p = 0.f;
    if (tid < 100)      p  = h3[tid]     * W4[tid];
    if (tid + 64 < 100) p += h3[tid+64]  * W4[tid+64];
#pragma unroll
    for (int off=32; off; off>>=1) p += __shfl_down(p, off);
    if (tid==0) out[g] = p + b4[0];
  }
}

extern "C" void kernel_launch(void* const* d_in, const int* in_sizes, int n_in,
                              void* d_out, int out_size, void* d_ws, size_t ws_size,
                              hipStream_t stream){
  const float* x  = (const float*)d_in[0];
  const int*   ei = (const int*)  d_in[1];
  const int* batch= (const int*)  d_in[2];
  const float* W1 = (const float*)d_in[4];
  const float* b1 = (const float*)d_in[5];
  const float* W2 = (const float*)d_in[6];
  const float* b2 = (const float*)d_in[7];
  const float* W3 = (const float*)d_in[8];
  const float* b3 = (const float*)d_in[9];
  const float* W4 = (const float*)d_in[10];
  const float* b4 = (const float*)d_in[11];
  float* out = (float*)d_out;

  int N = in_sizes[0]/3;
  int E = in_sizes[1]/2;
  int G = out_size;
  const int* src = ei;
  const int* dst = ei + E;
  int NP = ((N + 63)/64)*64;   // padded rows for mm2 tile overrun

  char* base = (char*)d_ws; size_t off = 0;
  auto alloc = [&](size_t bytes)->void*{
    void* p = base + off;
    off = (off + bytes + 255) & ~(size_t)255;
    return p;
  };
  // zero-init via memset: cnt only (pooled zeroed in k_count_wconv)
  int*   cnt      = (int*)  alloc((size_t)N*4);
  size_t zbytes   = off;
  float* pooled   = (float*)alloc((size_t)G*200*4);
  int*   rowstart = (int*)  alloc((size_t)(N+1)*4);
  int*   cursor   = (int*)  alloc((size_t)N*4);
  int*   bsum     = (int*)  alloc(4096);
  int*   colsrc   = (int*)  alloc((size_t)E*4);
  float4* dxp     = (float4*)alloc((size_t)N*16);
  float4* z1      = (float4*)alloc((size_t)N*16);
  unsigned short* a2h = (unsigned short*)alloc((size_t)NP*128*2);
  unsigned short* a2l = (unsigned short*)alloc((size_t)NP*128*2);
  unsigned short* w2th = (unsigned short*)alloc((size_t)224*128*2);
  unsigned short* w2tl = (unsigned short*)alloc((size_t)224*128*2);
  (void)ws_size; (void)n_in;

  hipMemsetAsync(base, 0, zbytes, stream);
  int gE = (E+255)/256;
  int gW = (224*128+255)/256;
  int poolN = G*200;
  int gP = (poolN+255)/256;
  k_count_wconv<<<gE+gW+gP,256,0,stream>>>(dst, cnt, E, W2, w2th, w2tl, pooled, poolN, gE, gW);
  int nb = (N+2047)/2048;
  k_scan1<<<nb,256,0,stream>>>(cnt, rowstart, bsum, N);
  k_scan3<<<(N+255)/256,256,0,stream>>>(bsum, cnt, x, rowstart, cursor, dxp, N, E, nb);
  k_fill<<<gE,256,0,stream>>>(src, dst, cursor, colsrc, E);
  k_z1<<<(N+255)/256,256,0,stream>>>(dxp, rowstart, colsrc, z1, N);
  k_agg2f<<<(N+7)/8,256,0,stream>>>(z1, rowstart, colsrc, W1, b1, a2h, a2l, N);
  int nwg = (N+31)/32;
  dim3 gmm(nwg, 2);
  k_mm2<<<gmm,128,0,stream>>>(a2h, a2l, w2th, w2tl, b2, batch, pooled, N, nwg);
  k_head<<<G,256,0,stream>>>(pooled, batch, W3, b3, W4, b4, out, N);
}